// Round 3
// baseline (898.387 us; speedup 1.0000x reference)
//
#include <hip/hip_runtime.h>
#include <hip/hip_bf16.h>
#include <math.h>

// ---------------- CSR build ----------------

__global__ void k_count(const int* __restrict__ dst, int* __restrict__ cnt, int E) {
    int e = blockIdx.x * 256 + threadIdx.x;
    if (e < E) atomicAdd(&cnt[dst[e]], 1);
}

__global__ void k_dinv(const int* __restrict__ cnt, float* __restrict__ dinv, int n) {
    int i = blockIdx.x * 256 + threadIdx.x;
    if (i < n) dinv[i] = 1.0f / sqrtf((float)cnt[i] + 1.0f);  // +1 self-loop
}

__global__ void k_scan_part(const int* __restrict__ cnt, int* __restrict__ offs,
                            int* __restrict__ parts, int n) {
    __shared__ int s[256];
    int i = blockIdx.x * 256 + threadIdx.x;
    int v = (i < n) ? cnt[i] : 0;
    s[threadIdx.x] = v;
    __syncthreads();
    #pragma unroll
    for (int d = 1; d < 256; d <<= 1) {
        int t = (threadIdx.x >= d) ? s[threadIdx.x - d] : 0;
        __syncthreads();
        s[threadIdx.x] += t;
        __syncthreads();
    }
    if (i < n) offs[i] = s[threadIdx.x] - v;        // block-local exclusive
    if (threadIdx.x == 255) parts[blockIdx.x] = s[255];
}

__global__ void k_scan_tops(int* __restrict__ parts, int np) {
    __shared__ int s[256];
    int tid = threadIdx.x;
    int v = (tid < np) ? parts[tid] : 0;
    s[tid] = v;
    __syncthreads();
    #pragma unroll
    for (int d = 1; d < 256; d <<= 1) {
        int t = (tid >= d) ? s[tid - d] : 0;
        __syncthreads();
        s[tid] += t;
        __syncthreads();
    }
    if (tid < np) parts[tid] = s[tid] - v;          // exclusive
}

__global__ void k_scan_add(int* __restrict__ offs, const int* __restrict__ parts,
                           int n, int e_total) {
    int i = blockIdx.x * 256 + threadIdx.x;
    if (i < n) offs[i] += parts[blockIdx.x];
    if (blockIdx.x == 0 && threadIdx.x == 0) offs[n] = e_total;
}

// csr entry = {src, 0.9*dinv[dst]*dinv[src] as bits}
__global__ void k_scatter(const int* __restrict__ dst, const int* __restrict__ src,
                          const int* __restrict__ offs, int* __restrict__ cur,
                          const float* __restrict__ dinv, int2* __restrict__ csr, int E) {
    int e = blockIdx.x * 256 + threadIdx.x;
    if (e < E) {
        int d = dst[e], s = src[e];
        int pos = offs[d] + atomicAdd(&cur[d], 1);
        float w = 0.9f * dinv[d] * dinv[s];
        csr[pos] = make_int2(s, __float_as_int(w));
    }
}

// ---------------- SpMM: support = 0.9*A_hat*h + 0.1*h0 ----------------
// One wave per destination node, lane owns float2 of H=128.
// CSR entries batch-loaded coalesced (64/wave), broadcast via v_readlane,
// 8 independent 512B gathers in flight.

__global__ __launch_bounds__(256)
void k_spmm(const int* __restrict__ offs, const int2* __restrict__ csr,
            const float* __restrict__ dinv, const float* __restrict__ h,
            const float* __restrict__ h0, float* __restrict__ sup, int n, int E) {
    int node = (blockIdx.x << 2) + (threadIdx.x >> 6);
    if (node >= n) return;
    int lane = threadIdx.x & 63;
    const float2* h2  = (const float2*)h;
    const float2* h02 = (const float2*)h0;
    float di = dinv[node];
    float2 v  = h2[(size_t)node * 64 + lane];
    float2 a0 = h02[(size_t)node * 64 + lane];
    float ws = 0.9f * di * di;
    float ax = ws * v.x + 0.1f * a0.x;
    float ay = ws * v.y + 0.1f * a0.y;
    int e = offs[node], end = offs[node + 1];
    while (e < end) {
        int nb = end - e;
        if (nb > 64) nb = 64;
        int2 ce = csr[min(e + lane, E - 1)];     // coalesced 512B batch load
        int i = 0;
        for (; i + 8 <= nb; i += 8) {
            float2 hv[8];
            float  wv[8];
            #pragma unroll
            for (int j = 0; j < 8; ++j) {
                int s = __builtin_amdgcn_readlane(ce.x, i + j);
                wv[j] = __int_as_float(__builtin_amdgcn_readlane(ce.y, i + j));
                hv[j] = h2[(size_t)s * 64 + lane];
            }
            #pragma unroll
            for (int j = 0; j < 8; ++j) {
                ax += wv[j] * hv[j].x;
                ay += wv[j] * hv[j].y;
            }
        }
        for (; i < nb; ++i) {
            int s = __builtin_amdgcn_readlane(ce.x, i);
            float w = __int_as_float(__builtin_amdgcn_readlane(ce.y, i));
            float2 hv = h2[(size_t)s * 64 + lane];
            ax += w * hv.x;
            ay += w * hv.y;
        }
        e += nb;
    }
    float2 o; o.x = ax; o.y = ay;
    ((float2*)sup)[(size_t)node * 64 + lane] = o;
}

// ---------------- W-resident 128x128 fp32 GEMM, fused residual+relu -------
// out[r][c] = relu( beta*(in@W)[r][c] + resid*in[r][c] + bias[c] )
// W (64KB) loaded to LDS once per block; grid-stride over 64-row tiles.
// 512 threads, 4x4 micro-tile. xT padded (stride 65) to break the
// transpose-write bank conflict.

#define XT_LD 65

template<bool RELU, bool DUAL>
__global__ __launch_bounds__(512, 1)
void gemm128w(const float* __restrict__ in, const float* __restrict__ W,
              const float* __restrict__ bias, float beta, float resid,
              float* __restrict__ out, float* __restrict__ out2,
              int M, int nTiles) {
    extern __shared__ float lds[];
    float* Ws = lds;                 // 128*128 floats (64KB)
    float* xT = lds + 128 * 128;     // [k][r] padded: 128*XT_LD floats

    const int tid = threadIdx.x;
    // load full W once
    {
        const float4* W4 = (const float4*)W;
        for (int i = tid; i < 4096; i += 512)      // 128*128/4
            ((float4*)Ws)[i] = W4[i];
    }
    const int tr = tid >> 5;    // 0..15 -> rows tr*4..tr*4+3
    const int tc = tid & 31;    // 0..31 -> cols tc*4..tc*4+3

    float bb[4] = {0.f, 0.f, 0.f, 0.f};
    if (bias) {
        #pragma unroll
        for (int j = 0; j < 4; ++j) bb[j] = bias[tc * 4 + j];
    }

    for (int t = blockIdx.x; t < nTiles; t += gridDim.x) {
        const int row0 = t * 64;
        __syncthreads();   // xT safe to overwrite; also guards W on first iter
        {
            const float4* in4 = (const float4*)in;
            for (int i = tid; i < 2048; i += 512) {   // 64 rows x 32 float4
                int r = i >> 5, c4 = i & 31;
                int gr = row0 + r;
                float4 v = make_float4(0.f, 0.f, 0.f, 0.f);
                if (gr < M) v = in4[(size_t)gr * 32 + c4];
                xT[(c4 * 4 + 0) * XT_LD + r] = v.x;
                xT[(c4 * 4 + 1) * XT_LD + r] = v.y;
                xT[(c4 * 4 + 2) * XT_LD + r] = v.z;
                xT[(c4 * 4 + 3) * XT_LD + r] = v.w;
            }
        }
        __syncthreads();

        float acc[4][4];
        #pragma unroll
        for (int i = 0; i < 4; ++i)
            #pragma unroll
            for (int j = 0; j < 4; ++j) acc[i][j] = 0.f;

        #pragma unroll 8
        for (int k = 0; k < 128; ++k) {
            float4 a = *(const float4*)&xT[k * XT_LD + tr * 4];
            float4 b = *(const float4*)&Ws[k * 128 + tc * 4];
            acc[0][0] += a.x * b.x; acc[0][1] += a.x * b.y; acc[0][2] += a.x * b.z; acc[0][3] += a.x * b.w;
            acc[1][0] += a.y * b.x; acc[1][1] += a.y * b.y; acc[1][2] += a.y * b.z; acc[1][3] += a.y * b.w;
            acc[2][0] += a.z * b.x; acc[2][1] += a.z * b.y; acc[2][2] += a.z * b.z; acc[2][3] += a.z * b.w;
            acc[3][0] += a.w * b.x; acc[3][1] += a.w * b.y; acc[3][2] += a.w * b.z; acc[3][3] += a.w * b.w;
        }

        #pragma unroll
        for (int i = 0; i < 4; ++i) {
            int r = row0 + tr * 4 + i;
            if (r < M) {
                // residual re-read from global (coalesced, L2-hot)
                float4 x = *(const float4*)&in[(size_t)r * 128 + tc * 4];
                float s0 = beta * acc[i][0] + resid * x.x + bb[0];
                float s1 = beta * acc[i][1] + resid * x.y + bb[1];
                float s2 = beta * acc[i][2] + resid * x.z + bb[2];
                float s3 = beta * acc[i][3] + resid * x.w + bb[3];
                if (RELU) {
                    s0 = fmaxf(s0, 0.f); s1 = fmaxf(s1, 0.f);
                    s2 = fmaxf(s2, 0.f); s3 = fmaxf(s3, 0.f);
                }
                float4 o; o.x = s0; o.y = s1; o.z = s2; o.w = s3;
                *(float4*)&out[(size_t)r * 128 + tc * 4] = o;
                if (DUAL) *(float4*)&out2[(size_t)r * 128 + tc * 4] = o;
            }
        }
    }
}

// ---------------- output GEMM: [M,128] @ [128,40] + b ----------------

__global__ __launch_bounds__(320)
void k_out(const float* __restrict__ h, const float* __restrict__ W,
           const float* __restrict__ b, float* __restrict__ out, int M, int C) {
    __shared__ float Ws[128 * 41];   // padded: bank-conflict-free scalar reads
    __shared__ float xs[32 * 132];   // padded rows, 16B-aligned float4 reads
    const int tid  = threadIdx.x;    // 320
    const int row0 = blockIdx.x * 32;

    for (int i = tid; i < 128 * 40; i += 320) {
        int k = i / 40, c = i % 40;
        Ws[k * 41 + c] = W[i];
    }
    {
        const float4* h4 = (const float4*)h;
        for (int i = tid; i < 1024; i += 320) {   // 32 rows x 32 float4
            int r = i >> 5, c4 = i & 31;
            int gr = row0 + r;
            float4 v = make_float4(0.f, 0.f, 0.f, 0.f);
            if (gr < M) v = h4[(size_t)gr * 32 + c4];
            *(float4*)&xs[r * 132 + c4 * 4] = v;
        }
    }
    __syncthreads();

    const int c  = tid % 40;
    const int rg = tid / 40;          // 0..7 -> rows rg*4..rg*4+3
    float acc[4] = {0.f, 0.f, 0.f, 0.f};
    #pragma unroll 4
    for (int k4 = 0; k4 < 32; ++k4) {
        float w0 = Ws[(k4 * 4 + 0) * 41 + c];
        float w1 = Ws[(k4 * 4 + 1) * 41 + c];
        float w2 = Ws[(k4 * 4 + 2) * 41 + c];
        float w3 = Ws[(k4 * 4 + 3) * 41 + c];
        #pragma unroll
        for (int i = 0; i < 4; ++i) {
            float4 x = *(const float4*)&xs[(rg * 4 + i) * 132 + k4 * 4];
            acc[i] += x.x * w0 + x.y * w1 + x.z * w2 + x.w * w3;
        }
    }
    float bb = b[c];
    #pragma unroll
    for (int i = 0; i < 4; ++i) {
        int r = row0 + rg * 4 + i;
        if (r < M) out[(size_t)r * C + c] = acc[i] + bb;
    }
}

// ---------------- host ----------------

extern "C" void kernel_launch(void* const* d_in, const int* in_sizes, int n_in,
                              void* d_out, int out_size, void* d_ws, size_t ws_size,
                              hipStream_t stream) {
    const float* x        = (const float*)d_in[0];
    const int*   ei       = (const int*)d_in[1];
    const float* W_in     = (const float*)d_in[2];
    const float* b_in     = (const float*)d_in[3];
    const float* W_layers = (const float*)d_in[4];
    const float* W_out    = (const float*)d_in[5];
    const float* b_out    = (const float*)d_in[6];
    float* out = (float*)d_out;

    const int H = 128;
    const int N = in_sizes[0] / H;             // 50000
    const int E = in_sizes[1] / 2;             // 800000
    const int L = in_sizes[4] / (H * H);       // 4
    const int C = in_sizes[5] / H;             // 40

    // workspace carve (256B aligned)
    char* p = (char*)d_ws;
    auto alloc = [&](size_t bytes) {
        char* r = p;
        p += (bytes + 255) & ~(size_t)255;
        return r;
    };
    int*   cnt   = (int*)alloc((size_t)N * 4);
    int*   offs  = (int*)alloc((size_t)(N + 1) * 4);
    int*   parts = (int*)alloc(256 * 4);
    int2*  csr   = (int2*)alloc((size_t)E * 8);
    float* dinv  = (float*)alloc((size_t)N * 4);
    float* h0    = (float*)alloc((size_t)N * H * 4);
    float* hA    = (float*)alloc((size_t)N * H * 4);
    float* hB    = (float*)alloc((size_t)N * H * 4);
    (void)ws_size;

    const int* ei0 = ei;        // destinations (row)
    const int* ei1 = ei + E;    // sources (col)

    const int nblkN = (N + 255) / 256;
    const int nblkE = (E + 255) / 256;

    hipMemsetAsync(cnt, 0, (size_t)N * 4, stream);
    k_count<<<nblkE, 256, 0, stream>>>(ei0, cnt, E);
    k_dinv<<<nblkN, 256, 0, stream>>>(cnt, dinv, N);
    k_scan_part<<<nblkN, 256, 0, stream>>>(cnt, offs, parts, N);
    k_scan_tops<<<1, 256, 0, stream>>>(parts, nblkN);
    k_scan_add<<<nblkN, 256, 0, stream>>>(offs, parts, N, E);
    hipMemsetAsync(cnt, 0, (size_t)N * 4, stream);
    k_scatter<<<nblkE, 256, 0, stream>>>(ei0, ei1, offs, cnt, dinv, csr, E);

    const int nTiles = (N + 63) / 64;
    const size_t gemm_lds = (size_t)(128 * 128 + 128 * XT_LD) * 4;  // ~96.5KB
    const int gemm_grid = 256;

    // input linear + relu -> hA, copy -> h0
    gemm128w<true, true><<<gemm_grid, 512, gemm_lds, stream>>>(
        x, W_in, b_in, 1.0f, 0.0f, hA, h0, N, nTiles);

    for (int l = 0; l < L; ++l) {
        float beta = logf(0.5f / (float)(l + 1) + 1.0f);
        k_spmm<<<(N + 3) / 4, 256, 0, stream>>>(offs, csr, dinv, hA, h0, hB, N, E);
        gemm128w<true, false><<<gemm_grid, 512, gemm_lds, stream>>>(
            hB, W_layers + (size_t)l * H * H, nullptr, beta, 1.0f - beta, hA, nullptr, N, nTiles);
    }

    k_out<<<(N + 31) / 32, 320, 0, stream>>>(hA, W_out, b_out, out, N, C);
}

// Round 5
// 507.040 us; speedup vs baseline: 1.7718x; 1.7718x over previous
//
#include <hip/hip_runtime.h>
#include <hip/hip_bf16.h>
#include <math.h>

typedef short short8 __attribute__((ext_vector_type(8)));
typedef float f32x4  __attribute__((ext_vector_type(4)));

__device__ __forceinline__ unsigned short f2bf(float f) {
    union { float f; unsigned u; } v; v.f = f;
    unsigned r = (v.u + 0x7FFFu + ((v.u >> 16) & 1u)) >> 16;
    return (unsigned short)r;
}
__device__ __forceinline__ float bf2f(unsigned short b) {
    union { unsigned u; float f; } v; v.u = ((unsigned)b) << 16; return v.f;
}

// ---------------- CSR build ----------------

__global__ void k_count(const int* __restrict__ dst, int* __restrict__ cnt, int E) {
    int e = blockIdx.x * 256 + threadIdx.x;
    if (e < E) atomicAdd(&cnt[dst[e]], 1);
}

__global__ void k_dinv(const int* __restrict__ cnt, float* __restrict__ dinv, int n) {
    int i = blockIdx.x * 256 + threadIdx.x;
    if (i < n) dinv[i] = 1.0f / sqrtf((float)cnt[i] + 1.0f);  // +1 self-loop
}

__global__ void k_scan_part(const int* __restrict__ cnt, int* __restrict__ offs,
                            int* __restrict__ parts, int n) {
    __shared__ int s[256];
    int i = blockIdx.x * 256 + threadIdx.x;
    int v = (i < n) ? cnt[i] : 0;
    s[threadIdx.x] = v;
    __syncthreads();
    #pragma unroll
    for (int d = 1; d < 256; d <<= 1) {
        int t = (threadIdx.x >= d) ? s[threadIdx.x - d] : 0;
        __syncthreads();
        s[threadIdx.x] += t;
        __syncthreads();
    }
    if (i < n) offs[i] = s[threadIdx.x] - v;        // block-local exclusive
    if (threadIdx.x == 255) parts[blockIdx.x] = s[255];
}

__global__ void k_scan_tops(int* __restrict__ parts, int np) {
    __shared__ int s[256];
    int tid = threadIdx.x;
    int v = (tid < np) ? parts[tid] : 0;
    s[tid] = v;
    __syncthreads();
    #pragma unroll
    for (int d = 1; d < 256; d <<= 1) {
        int t = (tid >= d) ? s[tid - d] : 0;
        __syncthreads();
        s[tid] += t;
        __syncthreads();
    }
    if (tid < np) parts[tid] = s[tid] - v;          // exclusive
}

__global__ void k_scan_add(int* __restrict__ offs, const int* __restrict__ parts,
                           int n, int e_total) {
    int i = blockIdx.x * 256 + threadIdx.x;
    if (i < n) offs[i] += parts[blockIdx.x];
    if (blockIdx.x == 0 && threadIdx.x == 0) offs[n] = e_total;
}

// csr entry = {src, 0.9*dinv[dst]*dinv[src] as bits}
__global__ void k_scatter(const int* __restrict__ dst, const int* __restrict__ src,
                          const int* __restrict__ offs, int* __restrict__ cur,
                          const float* __restrict__ dinv, int2* __restrict__ csr, int E) {
    int e = blockIdx.x * 256 + threadIdx.x;
    if (e < E) {
        int d = dst[e], s = src[e];
        int pos = offs[d] + atomicAdd(&cur[d], 1);
        float w = 0.9f * dinv[d] * dinv[s];
        csr[pos] = make_int2(s, __float_as_int(w));
    }
}

// ---------------- weight prep: transpose (+split for W_in) to bf16 --------
// blockIdx 0..3: Wt[l][n][k] = bf16(W_layers[l][k][n])
// blockIdx 4   : Wht[n][k] = hi(W_in[k][n]); Wlt[n][k] = lo(W_in[k][n])

__global__ void k_wprep(const float* __restrict__ Wl, const float* __restrict__ Win,
                        unsigned short* __restrict__ wt,
                        unsigned short* __restrict__ wht,
                        unsigned short* __restrict__ wlt) {
    int m = blockIdx.x;
    for (int i = threadIdx.x; i < 16384; i += 256) {
        int n = i >> 7, k = i & 127;
        if (m < 4) {
            wt[m * 16384 + n * 128 + k] = f2bf(Wl[m * 16384 + k * 128 + n]);
        } else {
            float f = Win[k * 128 + n];
            unsigned short h = f2bf(f);
            wht[n * 128 + k] = h;
            wlt[n * 128 + k] = f2bf(f - bf2f(h));
        }
    }
}

// ---------------- SpMM: support = 0.9*A_hat*h + 0.1*h0 ----------------
// One wave per destination node, lane owns float2 of H=128.
// CSR entries batch-loaded coalesced (64/wave), broadcast via readlane,
// 8 independent 512B gathers in flight.

__global__ __launch_bounds__(256)
void k_spmm(const int* __restrict__ offs, const int2* __restrict__ csr,
            const float* __restrict__ dinv, const float* __restrict__ h,
            const float* __restrict__ h0, float* __restrict__ sup, int n, int E) {
    int node = (blockIdx.x << 2) + (threadIdx.x >> 6);
    if (node >= n) return;
    int lane = threadIdx.x & 63;
    const float2* h2  = (const float2*)h;
    const float2* h02 = (const float2*)h0;
    float di = dinv[node];
    float2 v  = h2[(size_t)node * 64 + lane];
    float2 a0 = h02[(size_t)node * 64 + lane];
    float ws = 0.9f * di * di;
    float ax = ws * v.x + 0.1f * a0.x;
    float ay = ws * v.y + 0.1f * a0.y;
    int e = offs[node], end = offs[node + 1];
    while (e < end) {
        int nb = end - e;
        if (nb > 64) nb = 64;
        int2 ce = csr[min(e + lane, E - 1)];     // coalesced 512B batch load
        int i = 0;
        for (; i + 8 <= nb; i += 8) {
            float2 hv[8];
            float  wv[8];
            #pragma unroll
            for (int j = 0; j < 8; ++j) {
                int s = __builtin_amdgcn_readlane(ce.x, i + j);
                wv[j] = __int_as_float(__builtin_amdgcn_readlane(ce.y, i + j));
                hv[j] = h2[(size_t)s * 64 + lane];
            }
            #pragma unroll
            for (int j = 0; j < 8; ++j) {
                ax += wv[j] * hv[j].x;
                ay += wv[j] * hv[j].y;
            }
        }
        for (; i < nb; ++i) {
            int s = __builtin_amdgcn_readlane(ce.x, i);
            float w = __int_as_float(__builtin_amdgcn_readlane(ce.y, i));
            float2 hv = h2[(size_t)s * 64 + lane];
            ax += w * hv.x;
            ay += w * hv.y;
        }
        e += nb;
    }
    float2 o; o.x = ax; o.y = ay;
    ((float2*)sup)[(size_t)node * 64 + lane] = o;
}

// ---------------- MFMA GEMM: [M,128] @ [128,128], fused residual+relu -----
// SPLIT=1 (input layer): A = x as bf16 hi+lo, B = Wht/Wlt; out = relu(A@B + bias),
//                        written to out AND out2 (h0 copy).
// SPLIT=0 (gcn layer):   A = bf16(support), B = Wt;
//                        out = relu(beta*(A@B) + gamma*support).
// 64-row tile per block, 4 waves, v_mfma_f32_16x16x32_bf16, fp32 accum.
// LDS tiles XOR-swizzled on 16B chunks (chunk ^= row&7) -> conflict-free
// ds_read_b128 fragment reads (T2-style; without it reads are 16-way).

template<int SPLIT>
__global__ __launch_bounds__(256)
void gemm_mfma(const float* __restrict__ inA,
               const unsigned short* __restrict__ Bhi,
               const unsigned short* __restrict__ Blo,
               const float* __restrict__ bias,
               float beta, float gamma,
               float* __restrict__ out, float* __restrict__ out2, int M) {
    extern __shared__ char lds[];
    char* Ahi = lds;                                   // 64*128 bf16 = 16KB
    char* Alo = Ahi + 16384;                           // SPLIT only
    char* Whi = Ahi + (SPLIT ? 32768 : 16384);         // 128*128 bf16 = 32KB
    char* Wlo = Whi + 32768;                           // SPLIT only

    const int tid  = threadIdx.x;
    const int row0 = blockIdx.x * 64;

    // stage A: fp32 -> bf16 (hi[/lo]) with swizzle
    for (int c = tid; c < 1024; c += 256) {            // 64 rows x 16 chunks
        int row = c >> 4, k8 = c & 15;
        int grow = row0 + row;
        short8 hv = {0,0,0,0,0,0,0,0};
        short8 lv = {0,0,0,0,0,0,0,0};
        if (grow < M) {
            const float* s = &inA[(size_t)grow * 128 + k8 * 8];
            float4 f0 = *(const float4*)s;
            float4 f1 = *(const float4*)(s + 4);
            float ff[8] = {f0.x, f0.y, f0.z, f0.w, f1.x, f1.y, f1.z, f1.w};
            #pragma unroll
            for (int j = 0; j < 8; ++j) {
                unsigned short h = f2bf(ff[j]);
                hv[j] = (short)h;
                if (SPLIT) lv[j] = (short)f2bf(ff[j] - bf2f(h));
            }
        }
        int off = row * 256 + ((k8 ^ (row & 7)) << 4);
        *(short8*)(Ahi + off) = hv;
        if (SPLIT) *(short8*)(Alo + off) = lv;
    }
    // stage W: bf16 direct with swizzle
    for (int c = tid; c < 2048; c += 256) {            // 128 n-rows x 16 chunks
        int n = c >> 4, k8 = c & 15;
        int off = n * 256 + ((k8 ^ (n & 7)) << 4);
        *(short8*)(Whi + off) = *(const short8*)&Bhi[n * 128 + k8 * 8];
        if (SPLIT) *(short8*)(Wlo + off) = *(const short8*)&Blo[n * 128 + k8 * 8];
    }
    __syncthreads();

    const int lane = tid & 63;
    const int w    = tid >> 6;        // wave 0..3 -> cols w*32..w*32+31
    const int lr   = lane & 15;
    const int lg   = lane >> 4;

    f32x4 acc[4][2];
    #pragma unroll
    for (int m = 0; m < 4; ++m)
        #pragma unroll
        for (int n2 = 0; n2 < 2; ++n2) acc[m][n2] = (f32x4){0.f, 0.f, 0.f, 0.f};

    #pragma unroll
    for (int kk = 0; kk < 4; ++kk) {
        int k8 = kk * 4 + lg;
        short8 a[4], b[2], al[4], bl[2];
        #pragma unroll
        for (int m = 0; m < 4; ++m) {
            int row = m * 16 + lr;
            int off = row * 256 + ((k8 ^ (row & 7)) << 4);
            a[m] = *(const short8*)(Ahi + off);
            if (SPLIT) al[m] = *(const short8*)(Alo + off);
        }
        #pragma unroll
        for (int n2 = 0; n2 < 2; ++n2) {
            int n = (w * 2 + n2) * 16 + lr;
            int off = n * 256 + ((k8 ^ (n & 7)) << 4);
            b[n2] = *(const short8*)(Whi + off);
            if (SPLIT) bl[n2] = *(const short8*)(Wlo + off);
        }
        #pragma unroll
        for (int m = 0; m < 4; ++m)
            #pragma unroll
            for (int n2 = 0; n2 < 2; ++n2) {
                if (SPLIT) {
                    acc[m][n2] = __builtin_amdgcn_mfma_f32_16x16x32_bf16(al[m], b[n2], acc[m][n2], 0, 0, 0);
                    acc[m][n2] = __builtin_amdgcn_mfma_f32_16x16x32_bf16(a[m], bl[n2], acc[m][n2], 0, 0, 0);
                }
                acc[m][n2] = __builtin_amdgcn_mfma_f32_16x16x32_bf16(a[m], b[n2], acc[m][n2], 0, 0, 0);
            }
    }

    // epilogue: C/D layout col = lane&15, row = (lane>>4)*4 + reg
    #pragma unroll
    for (int m = 0; m < 4; ++m) {
        #pragma unroll
        for (int n2 = 0; n2 < 2; ++n2) {
            int col = (w * 2 + n2) * 16 + lr;
            #pragma unroll
            for (int r = 0; r < 4; ++r) {
                int row = row0 + m * 16 + lg * 4 + r;
                if (row < M) {
                    float d = acc[m][n2][r];
                    float o;
                    if (SPLIT) o = d + bias[col];
                    else       o = beta * d + gamma * inA[(size_t)row * 128 + col];
                    o = fmaxf(o, 0.f);
                    out[(size_t)row * 128 + col] = o;
                    if (SPLIT) out2[(size_t)row * 128 + col] = o;
                }
            }
        }
    }
}

// ---------------- output GEMM: [M,128] @ [128,40] + b (fp32) --------------

__global__ __launch_bounds__(320)
void k_out(const float* __restrict__ h, const float* __restrict__ W,
           const float* __restrict__ b, float* __restrict__ out, int M, int C) {
    __shared__ float Ws[128 * 41];
    __shared__ float xs[32 * 132];
    const int tid  = threadIdx.x;    // 320
    const int row0 = blockIdx.x * 32;

    for (int i = tid; i < 128 * 40; i += 320) {
        int k = i / 40, c = i % 40;
        Ws[k * 41 + c] = W[i];
    }
    {
        const float4* h4 = (const float4*)h;
        for (int i = tid; i < 1024; i += 320) {
            int r = i >> 5, c4 = i & 31;
            int gr = row0 + r;
            float4 v = make_float4(0.f, 0.f, 0.f, 0.f);
            if (gr < M) v = h4[(size_t)gr * 32 + c4];
            *(float4*)&xs[r * 132 + c4 * 4] = v;
        }
    }
    __syncthreads();

    const int c  = tid % 40;
    const int rg = tid / 40;
    float acc[4] = {0.f, 0.f, 0.f, 0.f};
    #pragma unroll 4
    for (int k4 = 0; k4 < 32; ++k4) {
        float w0 = Ws[(k4 * 4 + 0) * 41 + c];
        float w1 = Ws[(k4 * 4 + 1) * 41 + c];
        float w2 = Ws[(k4 * 4 + 2) * 41 + c];
        float w3 = Ws[(k4 * 4 + 3) * 41 + c];
        #pragma unroll
        for (int i = 0; i < 4; ++i) {
            float4 x = *(const float4*)&xs[(rg * 4 + i) * 132 + k4 * 4];
            acc[i] += x.x * w0 + x.y * w1 + x.z * w2 + x.w * w3;
        }
    }
    float bb = b[c];
    #pragma unroll
    for (int i = 0; i < 4; ++i) {
        int r = row0 + rg * 4 + i;
        if (r < M) out[(size_t)r * C + c] = acc[i] + bb;
    }
}

// ---------------- host ----------------

extern "C" void kernel_launch(void* const* d_in, const int* in_sizes, int n_in,
                              void* d_out, int out_size, void* d_ws, size_t ws_size,
                              hipStream_t stream) {
    const float* x        = (const float*)d_in[0];
    const int*   ei       = (const int*)d_in[1];
    const float* W_in     = (const float*)d_in[2];
    const float* b_in     = (const float*)d_in[3];
    const float* W_layers = (const float*)d_in[4];
    const float* W_out    = (const float*)d_in[5];
    const float* b_out    = (const float*)d_in[6];
    float* out = (float*)d_out;

    const int H = 128;
    const int N = in_sizes[0] / H;             // 50000
    const int E = in_sizes[1] / 2;             // 800000
    const int L = in_sizes[4] / (H * H);       // 4
    const int C = in_sizes[5] / H;             // 40

    char* p = (char*)d_ws;
    auto alloc = [&](size_t bytes) {
        char* r = p;
        p += (bytes + 255) & ~(size_t)255;
        return r;
    };
    int*   cnt   = (int*)alloc((size_t)N * 4);
    int*   offs  = (int*)alloc((size_t)(N + 1) * 4);
    int*   parts = (int*)alloc(256 * 4);
    int2*  csr   = (int2*)alloc((size_t)E * 8);
    float* dinv  = (float*)alloc((size_t)N * 4);
    float* h0    = (float*)alloc((size_t)N * H * 4);
    float* hA    = (float*)alloc((size_t)N * H * 4);
    float* hB    = (float*)alloc((size_t)N * H * 4);
    unsigned short* wt  = (unsigned short*)alloc((size_t)L * H * H * 2);
    unsigned short* wht = (unsigned short*)alloc((size_t)H * H * 2);
    unsigned short* wlt = (unsigned short*)alloc((size_t)H * H * 2);
    (void)ws_size;

    const int* ei0 = ei;        // destinations (row)
    const int* ei1 = ei + E;    // sources (col)

    const int nblkN = (N + 255) / 256;
    const int nblkE = (E + 255) / 256;

    k_wprep<<<5, 256, 0, stream>>>(W_layers, W_in, wt, wht, wlt);

    hipMemsetAsync(cnt, 0, (size_t)N * 4, stream);
    k_count<<<nblkE, 256, 0, stream>>>(ei0, cnt, E);
    k_dinv<<<nblkN, 256, 0, stream>>>(cnt, dinv, N);
    k_scan_part<<<nblkN, 256, 0, stream>>>(cnt, offs, parts, N);
    k_scan_tops<<<1, 256, 0, stream>>>(parts, nblkN);
    k_scan_add<<<nblkN, 256, 0, stream>>>(offs, parts, N, E);
    hipMemsetAsync(cnt, 0, (size_t)N * 4, stream);
    k_scatter<<<nblkE, 256, 0, stream>>>(ei0, ei1, offs, cnt, dinv, csr, E);

    const int nTiles = (N + 63) / 64;

    // input linear (split-bf16, fp32-grade) + relu -> hA, copy -> h0
    gemm_mfma<1><<<nTiles, 256, 96 * 1024, stream>>>(
        x, wht, wlt, b_in, 0.f, 0.f, hA, h0, N);

    for (int l = 0; l < L; ++l) {
        float beta = logf(0.5f / (float)(l + 1) + 1.0f);
        k_spmm<<<(N + 3) / 4, 256, 0, stream>>>(offs, csr, dinv, hA, h0, hB, N, E);
        gemm_mfma<0><<<nTiles, 256, 48 * 1024, stream>>>(
            hB, wt + (size_t)l * H * H, nullptr, nullptr,
            beta, 1.0f - beta, hA, nullptr, N);
    }

    k_out<<<(N + 31) / 32, 320, 0, stream>>>(hA, W_out, b_out, out, N, C);
}

// Round 6
// 421.616 us; speedup vs baseline: 2.1308x; 1.2026x over previous
//
#include <hip/hip_runtime.h>
#include <hip/hip_bf16.h>
#include <math.h>

typedef short short8 __attribute__((ext_vector_type(8)));
typedef float f32x4  __attribute__((ext_vector_type(4)));

__device__ __forceinline__ unsigned short f2bf(float f) {
    union { float f; unsigned u; } v; v.f = f;
    unsigned r = (v.u + 0x7FFFu + ((v.u >> 16) & 1u)) >> 16;
    return (unsigned short)r;
}
__device__ __forceinline__ float bf2f(unsigned short b) {
    union { unsigned u; float f; } v; v.u = ((unsigned)b) << 16; return v.f;
}

// ---------------- CSR build ----------------

__global__ void k_count(const int* __restrict__ dst, int* __restrict__ cnt, int E) {
    int e = blockIdx.x * 256 + threadIdx.x;
    if (e < E) atomicAdd(&cnt[dst[e]], 1);
}

__global__ void k_dinv(const int* __restrict__ cnt, float* __restrict__ dinv, int n) {
    int i = blockIdx.x * 256 + threadIdx.x;
    if (i < n) dinv[i] = 1.0f / sqrtf((float)cnt[i] + 1.0f);  // +1 self-loop
}

__global__ void k_scan_part(const int* __restrict__ cnt, int* __restrict__ offs,
                            int* __restrict__ parts, int n) {
    __shared__ int s[256];
    int i = blockIdx.x * 256 + threadIdx.x;
    int v = (i < n) ? cnt[i] : 0;
    s[threadIdx.x] = v;
    __syncthreads();
    #pragma unroll
    for (int d = 1; d < 256; d <<= 1) {
        int t = (threadIdx.x >= d) ? s[threadIdx.x - d] : 0;
        __syncthreads();
        s[threadIdx.x] += t;
        __syncthreads();
    }
    if (i < n) offs[i] = s[threadIdx.x] - v;        // block-local exclusive
    if (threadIdx.x == 255) parts[blockIdx.x] = s[255];
}

__global__ void k_scan_tops(int* __restrict__ parts, int np) {
    __shared__ int s[256];
    int tid = threadIdx.x;
    int v = (tid < np) ? parts[tid] : 0;
    s[tid] = v;
    __syncthreads();
    #pragma unroll
    for (int d = 1; d < 256; d <<= 1) {
        int t = (tid >= d) ? s[tid - d] : 0;
        __syncthreads();
        s[tid] += t;
        __syncthreads();
    }
    if (tid < np) parts[tid] = s[tid] - v;          // exclusive
}

__global__ void k_scan_add(int* __restrict__ offs, const int* __restrict__ parts,
                           int n, int e_total) {
    int i = blockIdx.x * 256 + threadIdx.x;
    if (i < n) offs[i] += parts[blockIdx.x];
    if (blockIdx.x == 0 && threadIdx.x == 0) offs[n] = e_total;
}

// csr entry = {src, 0.9*dinv[dst]*dinv[src] as bits}
__global__ void k_scatter(const int* __restrict__ dst, const int* __restrict__ src,
                          const int* __restrict__ offs, int* __restrict__ cur,
                          const float* __restrict__ dinv, int2* __restrict__ csr, int E) {
    int e = blockIdx.x * 256 + threadIdx.x;
    if (e < E) {
        int d = dst[e], s = src[e];
        int pos = offs[d] + atomicAdd(&cur[d], 1);
        float w = 0.9f * dinv[d] * dinv[s];
        csr[pos] = make_int2(s, __float_as_int(w));
    }
}

// ---------------- weight prep: transpose (+split for W_in) to bf16 --------

__global__ void k_wprep(const float* __restrict__ Wl, const float* __restrict__ Win,
                        unsigned short* __restrict__ wt,
                        unsigned short* __restrict__ wht,
                        unsigned short* __restrict__ wlt) {
    int m = blockIdx.x;
    for (int i = threadIdx.x; i < 16384; i += 256) {
        int n = i >> 7, k = i & 127;
        if (m < 4) {
            wt[m * 16384 + n * 128 + k] = f2bf(Wl[m * 16384 + k * 128 + n]);
        } else {
            float f = Win[k * 128 + n];
            unsigned short h = f2bf(f);
            wht[n * 128 + k] = h;
            wlt[n * 128 + k] = f2bf(f - bf2f(h));
        }
    }
}

// ---------------- SpMM: support = 0.9*A_hat*h + 0.1*h0 ----------------
// One wave per destination node; lane owns features [2*lane, 2*lane+1].
// Neighbor rows gathered from the bf16 mirror hb (256B/edge, 2 lines);
// self term + h0 residual read fp32 (coalesced). CSR batch-loaded 64/wave,
// broadcast via readlane; 8/4/2-deep tiers keep gathers in flight.

__global__ __launch_bounds__(256)
void k_spmm(const int* __restrict__ offs, const int2* __restrict__ csr,
            const float* __restrict__ h, const unsigned short* __restrict__ hb,
            const float* __restrict__ h0, const float* __restrict__ dinv,
            float* __restrict__ sup, int n, int E) {
    int node = (blockIdx.x << 2) + (threadIdx.x >> 6);
    if (node >= n) return;
    int lane = threadIdx.x & 63;
    const float2* h2  = (const float2*)h;
    const float2* h02 = (const float2*)h0;
    float di = dinv[node];
    float2 v  = h2[(size_t)node * 64 + lane];
    float2 a0 = h02[(size_t)node * 64 + lane];
    float ws = 0.9f * di * di;
    float ax = ws * v.x + 0.1f * a0.x;
    float ay = ws * v.y + 0.1f * a0.y;
    int e = offs[node], end = offs[node + 1];
    while (e < end) {
        int nb = end - e;
        if (nb > 64) nb = 64;
        int2 ce = csr[min(e + lane, E - 1)];     // coalesced 512B batch load
        int i = 0;
        for (; i + 8 <= nb; i += 8) {
            unsigned g[8]; float wv[8];
            #pragma unroll
            for (int j = 0; j < 8; ++j) {
                int s = __builtin_amdgcn_readlane(ce.x, i + j);
                wv[j] = __int_as_float(__builtin_amdgcn_readlane(ce.y, i + j));
                g[j] = *(const unsigned*)&hb[(size_t)s * 128 + (lane << 1)];
            }
            #pragma unroll
            for (int j = 0; j < 8; ++j) {
                ax += wv[j] * bf2f((unsigned short)(g[j] & 0xffffu));
                ay += wv[j] * bf2f((unsigned short)(g[j] >> 16));
            }
        }
        for (; i + 4 <= nb; i += 4) {
            unsigned g[4]; float wv[4];
            #pragma unroll
            for (int j = 0; j < 4; ++j) {
                int s = __builtin_amdgcn_readlane(ce.x, i + j);
                wv[j] = __int_as_float(__builtin_amdgcn_readlane(ce.y, i + j));
                g[j] = *(const unsigned*)&hb[(size_t)s * 128 + (lane << 1)];
            }
            #pragma unroll
            for (int j = 0; j < 4; ++j) {
                ax += wv[j] * bf2f((unsigned short)(g[j] & 0xffffu));
                ay += wv[j] * bf2f((unsigned short)(g[j] >> 16));
            }
        }
        for (; i + 2 <= nb; i += 2) {
            unsigned g[2]; float wv[2];
            #pragma unroll
            for (int j = 0; j < 2; ++j) {
                int s = __builtin_amdgcn_readlane(ce.x, i + j);
                wv[j] = __int_as_float(__builtin_amdgcn_readlane(ce.y, i + j));
                g[j] = *(const unsigned*)&hb[(size_t)s * 128 + (lane << 1)];
            }
            #pragma unroll
            for (int j = 0; j < 2; ++j) {
                ax += wv[j] * bf2f((unsigned short)(g[j] & 0xffffu));
                ay += wv[j] * bf2f((unsigned short)(g[j] >> 16));
            }
        }
        for (; i < nb; ++i) {
            int s = __builtin_amdgcn_readlane(ce.x, i);
            float w = __int_as_float(__builtin_amdgcn_readlane(ce.y, i));
            unsigned g = *(const unsigned*)&hb[(size_t)s * 128 + (lane << 1)];
            ax += w * bf2f((unsigned short)(g & 0xffffu));
            ay += w * bf2f((unsigned short)(g >> 16));
        }
        e += nb;
    }
    float2 o; o.x = ax; o.y = ay;
    ((float2*)sup)[(size_t)node * 64 + lane] = o;
}

// ---------------- MFMA GEMM: [M,128] @ [128,128], fused residual+relu -----
// SPLIT=1: A = x as bf16 hi+lo, B = Wht/Wlt; out = relu(A@B + bias) -> out,
//          out2 (h0), outbf (bf16 mirror).
// SPLIT=0: A = bf16(support), B = Wt; out = relu(beta*(A@B) + gamma*support)
//          -> out, outbf (bf16 mirror, nullptr on last layer).

template<int SPLIT>
__global__ __launch_bounds__(256)
void gemm_mfma(const float* __restrict__ inA,
               const unsigned short* __restrict__ Bhi,
               const unsigned short* __restrict__ Blo,
               const float* __restrict__ bias,
               float beta, float gamma,
               float* __restrict__ out, float* __restrict__ out2,
               unsigned short* __restrict__ outbf, int M) {
    extern __shared__ char lds[];
    char* Ahi = lds;                                   // 64*128 bf16 = 16KB
    char* Alo = Ahi + 16384;                           // SPLIT only
    char* Whi = Ahi + (SPLIT ? 32768 : 16384);         // 128*128 bf16 = 32KB
    char* Wlo = Whi + 32768;                           // SPLIT only

    const int tid  = threadIdx.x;
    const int row0 = blockIdx.x * 64;

    // stage A: fp32 -> bf16 (hi[/lo]) with swizzle
    for (int c = tid; c < 1024; c += 256) {            // 64 rows x 16 chunks
        int row = c >> 4, k8 = c & 15;
        int grow = row0 + row;
        short8 hv = {0,0,0,0,0,0,0,0};
        short8 lv = {0,0,0,0,0,0,0,0};
        if (grow < M) {
            const float* s = &inA[(size_t)grow * 128 + k8 * 8];
            float4 f0 = *(const float4*)s;
            float4 f1 = *(const float4*)(s + 4);
            float ff[8] = {f0.x, f0.y, f0.z, f0.w, f1.x, f1.y, f1.z, f1.w};
            #pragma unroll
            for (int j = 0; j < 8; ++j) {
                unsigned short h = f2bf(ff[j]);
                hv[j] = (short)h;
                if (SPLIT) lv[j] = (short)f2bf(ff[j] - bf2f(h));
            }
        }
        int off = row * 256 + ((k8 ^ (row & 7)) << 4);
        *(short8*)(Ahi + off) = hv;
        if (SPLIT) *(short8*)(Alo + off) = lv;
    }
    // stage W: bf16 direct with swizzle
    for (int c = tid; c < 2048; c += 256) {            // 128 n-rows x 16 chunks
        int n = c >> 4, k8 = c & 15;
        int off = n * 256 + ((k8 ^ (n & 7)) << 4);
        *(short8*)(Whi + off) = *(const short8*)&Bhi[n * 128 + k8 * 8];
        if (SPLIT) *(short8*)(Wlo + off) = *(const short8*)&Blo[n * 128 + k8 * 8];
    }
    __syncthreads();

    const int lane = tid & 63;
    const int w    = tid >> 6;        // wave 0..3 -> cols w*32..w*32+31
    const int lr   = lane & 15;
    const int lg   = lane >> 4;

    f32x4 acc[4][2];
    #pragma unroll
    for (int m = 0; m < 4; ++m)
        #pragma unroll
        for (int n2 = 0; n2 < 2; ++n2) acc[m][n2] = (f32x4){0.f, 0.f, 0.f, 0.f};

    #pragma unroll
    for (int kk = 0; kk < 4; ++kk) {
        int k8 = kk * 4 + lg;
        short8 a[4], b[2], al[4], bl[2];
        #pragma unroll
        for (int m = 0; m < 4; ++m) {
            int row = m * 16 + lr;
            int off = row * 256 + ((k8 ^ (row & 7)) << 4);
            a[m] = *(const short8*)(Ahi + off);
            if (SPLIT) al[m] = *(const short8*)(Alo + off);
        }
        #pragma unroll
        for (int n2 = 0; n2 < 2; ++n2) {
            int n = (w * 2 + n2) * 16 + lr;
            int off = n * 256 + ((k8 ^ (n & 7)) << 4);
            b[n2] = *(const short8*)(Whi + off);
            if (SPLIT) bl[n2] = *(const short8*)(Blo ? Wlo : Wlo + 0);
            if (SPLIT) bl[n2] = *(const short8*)(Wlo + off);
        }
        #pragma unroll
        for (int m = 0; m < 4; ++m)
            #pragma unroll
            for (int n2 = 0; n2 < 2; ++n2) {
                if (SPLIT) {
                    acc[m][n2] = __builtin_amdgcn_mfma_f32_16x16x32_bf16(al[m], b[n2], acc[m][n2], 0, 0, 0);
                    acc[m][n2] = __builtin_amdgcn_mfma_f32_16x16x32_bf16(a[m], bl[n2], acc[m][n2], 0, 0, 0);
                }
                acc[m][n2] = __builtin_amdgcn_mfma_f32_16x16x32_bf16(a[m], b[n2], acc[m][n2], 0, 0, 0);
            }
    }

    // epilogue: C/D layout col = lane&15, row = (lane>>4)*4 + reg
    #pragma unroll
    for (int m = 0; m < 4; ++m) {
        #pragma unroll
        for (int n2 = 0; n2 < 2; ++n2) {
            int col = (w * 2 + n2) * 16 + lr;
            #pragma unroll
            for (int r = 0; r < 4; ++r) {
                int row = row0 + m * 16 + lg * 4 + r;
                if (row < M) {
                    float d = acc[m][n2][r];
                    float o;
                    if (SPLIT) o = d + bias[col];
                    else       o = beta * d + gamma * inA[(size_t)row * 128 + col];
                    o = fmaxf(o, 0.f);
                    out[(size_t)row * 128 + col] = o;
                    if (outbf) outbf[(size_t)row * 128 + col] = f2bf(o);
                    if (SPLIT) out2[(size_t)row * 128 + col] = o;
                }
            }
        }
    }
}

// ---------------- output GEMM: [M,128] @ [128,40] + b (fp32) --------------

__global__ __launch_bounds__(320)
void k_out(const float* __restrict__ h, const float* __restrict__ W,
           const float* __restrict__ b, float* __restrict__ out, int M, int C) {
    __shared__ float Ws[128 * 41];
    __shared__ float xs[32 * 132];
    const int tid  = threadIdx.x;    // 320
    const int row0 = blockIdx.x * 32;

    for (int i = tid; i < 128 * 40; i += 320) {
        int k = i / 40, c = i % 40;
        Ws[k * 41 + c] = W[i];
    }
    {
        const float4* h4 = (const float4*)h;
        for (int i = tid; i < 1024; i += 320) {
            int r = i >> 5, c4 = i & 31;
            int gr = row0 + r;
            float4 v = make_float4(0.f, 0.f, 0.f, 0.f);
            if (gr < M) v = h4[(size_t)gr * 32 + c4];
            *(float4*)&xs[r * 132 + c4 * 4] = v;
        }
    }
    __syncthreads();

    const int c  = tid % 40;
    const int rg = tid / 40;
    float acc[4] = {0.f, 0.f, 0.f, 0.f};
    #pragma unroll 4
    for (int k4 = 0; k4 < 32; ++k4) {
        float w0 = Ws[(k4 * 4 + 0) * 41 + c];
        float w1 = Ws[(k4 * 4 + 1) * 41 + c];
        float w2 = Ws[(k4 * 4 + 2) * 41 + c];
        float w3 = Ws[(k4 * 4 + 3) * 41 + c];
        #pragma unroll
        for (int i = 0; i < 4; ++i) {
            float4 x = *(const float4*)&xs[(rg * 4 + i) * 132 + k4 * 4];
            acc[i] += x.x * w0 + x.y * w1 + x.z * w2 + x.w * w3;
        }
    }
    float bb = b[c];
    #pragma unroll
    for (int i = 0; i < 4; ++i) {
        int r = row0 + rg * 4 + i;
        if (r < M) out[(size_t)r * C + c] = acc[i] + bb;
    }
}

// ---------------- host ----------------

extern "C" void kernel_launch(void* const* d_in, const int* in_sizes, int n_in,
                              void* d_out, int out_size, void* d_ws, size_t ws_size,
                              hipStream_t stream) {
    const float* x        = (const float*)d_in[0];
    const int*   ei       = (const int*)d_in[1];
    const float* W_in     = (const float*)d_in[2];
    const float* b_in     = (const float*)d_in[3];
    const float* W_layers = (const float*)d_in[4];
    const float* W_out    = (const float*)d_in[5];
    const float* b_out    = (const float*)d_in[6];
    float* out = (float*)d_out;

    const int H = 128;
    const int N = in_sizes[0] / H;             // 50000
    const int E = in_sizes[1] / 2;             // 800000
    const int L = in_sizes[4] / (H * H);       // 4
    const int C = in_sizes[5] / H;             // 40

    char* p = (char*)d_ws;
    auto alloc = [&](size_t bytes) {
        char* r = p;
        p += (bytes + 255) & ~(size_t)255;
        return r;
    };
    int*   cnt   = (int*)alloc((size_t)N * 4);
    int*   offs  = (int*)alloc((size_t)(N + 1) * 4);
    int*   parts = (int*)alloc(256 * 4);
    int2*  csr   = (int2*)alloc((size_t)E * 8);
    float* dinv  = (float*)alloc((size_t)N * 4);
    float* h0    = (float*)alloc((size_t)N * H * 4);
    float* hA    = (float*)alloc((size_t)N * H * 4);
    float* hB    = (float*)alloc((size_t)N * H * 4);
    unsigned short* hbf = (unsigned short*)alloc((size_t)N * H * 2);
    unsigned short* wt  = (unsigned short*)alloc((size_t)L * H * H * 2);
    unsigned short* wht = (unsigned short*)alloc((size_t)H * H * 2);
    unsigned short* wlt = (unsigned short*)alloc((size_t)H * H * 2);
    (void)ws_size;

    const int* ei0 = ei;        // destinations (row)
    const int* ei1 = ei + E;    // sources (col)

    const int nblkN = (N + 255) / 256;
    const int nblkE = (E + 255) / 256;

    k_wprep<<<5, 256, 0, stream>>>(W_layers, W_in, wt, wht, wlt);

    hipMemsetAsync(cnt, 0, (size_t)N * 4, stream);
    k_count<<<nblkE, 256, 0, stream>>>(ei0, cnt, E);
    k_dinv<<<nblkN, 256, 0, stream>>>(cnt, dinv, N);
    k_scan_part<<<nblkN, 256, 0, stream>>>(cnt, offs, parts, N);
    k_scan_tops<<<1, 256, 0, stream>>>(parts, nblkN);
    k_scan_add<<<nblkN, 256, 0, stream>>>(offs, parts, N, E);
    hipMemsetAsync(cnt, 0, (size_t)N * 4, stream);
    k_scatter<<<nblkE, 256, 0, stream>>>(ei0, ei1, offs, cnt, dinv, csr, E);

    const int nTiles = (N + 63) / 64;

    // input linear (split-bf16, fp32-grade) + relu -> hA, h0, hbf
    gemm_mfma<1><<<nTiles, 256, 96 * 1024, stream>>>(
        x, wht, wlt, b_in, 0.f, 0.f, hA, h0, hbf, N);

    for (int l = 0; l < L; ++l) {
        float beta = logf(0.5f / (float)(l + 1) + 1.0f);
        k_spmm<<<(N + 3) / 4, 256, 0, stream>>>(offs, csr, hA, hbf, h0, dinv, hB, N, E);
        gemm_mfma<0><<<nTiles, 256, 48 * 1024, stream>>>(
            hB, wt + (size_t)l * H * H, nullptr, nullptr,
            beta, 1.0f - beta, hA, nullptr, (l < L - 1) ? hbf : nullptr, N);
    }

    k_out<<<(N + 31) / 32, 320, 0, stream>>>(hA, W_out, b_out, out, N, C);
}

// Round 7
// 399.738 us; speedup vs baseline: 2.2474x; 1.0547x over previous
//
#include <hip/hip_runtime.h>
#include <hip/hip_bf16.h>
#include <hip/hip_fp16.h>
#include <math.h>

typedef short short8 __attribute__((ext_vector_type(8)));
typedef float f32x4  __attribute__((ext_vector_type(4)));

__device__ __forceinline__ unsigned short f2bf(float f) {
    union { float f; unsigned u; } v; v.f = f;
    unsigned r = (v.u + 0x7FFFu + ((v.u >> 16) & 1u)) >> 16;
    return (unsigned short)r;
}
__device__ __forceinline__ float bf2f(unsigned short b) {
    union { unsigned u; float f; } v; v.u = ((unsigned)b) << 16; return v.f;
}

// ---------------- CSR build ----------------

__global__ void k_count(const int* __restrict__ dst, int* __restrict__ cnt, int E) {
    int e = blockIdx.x * 256 + threadIdx.x;
    if (e < E) atomicAdd(&cnt[dst[e]], 1);
}

__global__ void k_dinv(const int* __restrict__ cnt, float* __restrict__ dinv, int n) {
    int i = blockIdx.x * 256 + threadIdx.x;
    if (i < n) dinv[i] = 1.0f / sqrtf((float)cnt[i] + 1.0f);  // +1 self-loop
}

__global__ void k_scan_part(const int* __restrict__ cnt, int* __restrict__ offs,
                            int* __restrict__ parts, int n) {
    __shared__ int s[256];
    int i = blockIdx.x * 256 + threadIdx.x;
    int v = (i < n) ? cnt[i] : 0;
    s[threadIdx.x] = v;
    __syncthreads();
    #pragma unroll
    for (int d = 1; d < 256; d <<= 1) {
        int t = (threadIdx.x >= d) ? s[threadIdx.x - d] : 0;
        __syncthreads();
        s[threadIdx.x] += t;
        __syncthreads();
    }
    if (i < n) offs[i] = s[threadIdx.x] - v;        // block-local exclusive
    if (threadIdx.x == 255) parts[blockIdx.x] = s[255];
}

__global__ void k_scan_tops(int* __restrict__ parts, int np) {
    __shared__ int s[256];
    int tid = threadIdx.x;
    int v = (tid < np) ? parts[tid] : 0;
    s[tid] = v;
    __syncthreads();
    #pragma unroll
    for (int d = 1; d < 256; d <<= 1) {
        int t = (tid >= d) ? s[tid - d] : 0;
        __syncthreads();
        s[tid] += t;
        __syncthreads();
    }
    if (tid < np) parts[tid] = s[tid] - v;          // exclusive
}

__global__ void k_scan_add(int* __restrict__ offs, const int* __restrict__ parts,
                           int n, int e_total) {
    int i = blockIdx.x * 256 + threadIdx.x;
    if (i < n) offs[i] += parts[blockIdx.x];
    if (blockIdx.x == 0 && threadIdx.x == 0) offs[n] = e_total;
}

// csr entry (4B) = fp16(0.9*dinv[d]*dinv[s]) << 16 | src   (src < 65536)
__global__ void k_scatter(const int* __restrict__ dst, const int* __restrict__ src,
                          const int* __restrict__ offs, int* __restrict__ cur,
                          const float* __restrict__ dinv, unsigned* __restrict__ csr, int E) {
    int e = blockIdx.x * 256 + threadIdx.x;
    if (e < E) {
        int d = dst[e], s = src[e];
        int pos = offs[d] + atomicAdd(&cur[d], 1);
        float w = 0.9f * dinv[d] * dinv[s];
        unsigned hw = (unsigned)__half_as_ushort(__float2half(w));
        csr[pos] = (hw << 16) | (unsigned)s;
    }
}

// ---------------- weight prep: transpose (+split for W_in) to bf16 --------

__global__ void k_wprep(const float* __restrict__ Wl, const float* __restrict__ Win,
                        unsigned short* __restrict__ wt,
                        unsigned short* __restrict__ wht,
                        unsigned short* __restrict__ wlt) {
    int m = blockIdx.x;
    for (int i = threadIdx.x; i < 16384; i += 256) {
        int n = i >> 7, k = i & 127;
        if (m < 4) {
            wt[m * 16384 + n * 128 + k] = f2bf(Wl[m * 16384 + k * 128 + n]);
        } else {
            float f = Win[k * 128 + n];
            unsigned short h = f2bf(f);
            wht[n * 128 + k] = h;
            wlt[n * 128 + k] = f2bf(f - bf2f(h));
        }
    }
}

// ---------------- SpMM: support = 0.9*A_hat*h + 0.1*h0 ----------------
// HALF-WAVE per node: lanes [0..31] -> node A, [32..63] -> node B.
// Each lane owns 4 bf16 features (8B gather) -> one load instruction
// services TWO edges. CSR batch-loaded 32/half-wave; entry broadcast via
// __shfl(width=32); 8/4/2/1 tiers keep gathers in flight.

__global__ __launch_bounds__(256)
void k_spmm(const int* __restrict__ offs, const unsigned* __restrict__ csr,
            const float* __restrict__ h, const unsigned short* __restrict__ hb,
            const float* __restrict__ h0, const float* __restrict__ dinv,
            float* __restrict__ sup, int n, int E) {
    int node = blockIdx.x * 8 + (threadIdx.x >> 5);
    if (node >= n) return;
    int l32 = threadIdx.x & 31;
    const float4* h4  = (const float4*)h;
    const float4* h04 = (const float4*)h0;
    float di = dinv[node];
    float4 v  = h4[(size_t)node * 32 + l32];
    float4 a0 = h04[(size_t)node * 32 + l32];
    float ws = 0.9f * di * di;
    float ax = ws * v.x + 0.1f * a0.x;
    float ay = ws * v.y + 0.1f * a0.y;
    float az = ws * v.z + 0.1f * a0.z;
    float aw = ws * v.w + 0.1f * a0.w;
    int e = offs[node], end = offs[node + 1];
    while (e < end) {
        int nb = end - e;
        if (nb > 32) nb = 32;
        unsigned ce = csr[min(e + l32, E - 1)];   // coalesced 128B per half
        int i = 0;
        for (; i + 8 <= nb; i += 8) {
            uint2 g[8]; float wv[8];
            #pragma unroll
            for (int j = 0; j < 8; ++j) {
                unsigned u = __shfl(ce, i + j, 32);
                wv[j] = __half2float(__ushort_as_half((unsigned short)(u >> 16)));
                g[j] = *(const uint2*)&hb[((size_t)(u & 0xffffu) << 7) + (l32 << 2)];
            }
            #pragma unroll
            for (int j = 0; j < 8; ++j) {
                ax += wv[j] * bf2f((unsigned short)(g[j].x & 0xffffu));
                ay += wv[j] * bf2f((unsigned short)(g[j].x >> 16));
                az += wv[j] * bf2f((unsigned short)(g[j].y & 0xffffu));
                aw += wv[j] * bf2f((unsigned short)(g[j].y >> 16));
            }
        }
        for (; i + 4 <= nb; i += 4) {
            uint2 g[4]; float wv[4];
            #pragma unroll
            for (int j = 0; j < 4; ++j) {
                unsigned u = __shfl(ce, i + j, 32);
                wv[j] = __half2float(__ushort_as_half((unsigned short)(u >> 16)));
                g[j] = *(const uint2*)&hb[((size_t)(u & 0xffffu) << 7) + (l32 << 2)];
            }
            #pragma unroll
            for (int j = 0; j < 4; ++j) {
                ax += wv[j] * bf2f((unsigned short)(g[j].x & 0xffffu));
                ay += wv[j] * bf2f((unsigned short)(g[j].x >> 16));
                az += wv[j] * bf2f((unsigned short)(g[j].y & 0xffffu));
                aw += wv[j] * bf2f((unsigned short)(g[j].y >> 16));
            }
        }
        for (; i + 2 <= nb; i += 2) {
            uint2 g[2]; float wv[2];
            #pragma unroll
            for (int j = 0; j < 2; ++j) {
                unsigned u = __shfl(ce, i + j, 32);
                wv[j] = __half2float(__ushort_as_half((unsigned short)(u >> 16)));
                g[j] = *(const uint2*)&hb[((size_t)(u & 0xffffu) << 7) + (l32 << 2)];
            }
            #pragma unroll
            for (int j = 0; j < 2; ++j) {
                ax += wv[j] * bf2f((unsigned short)(g[j].x & 0xffffu));
                ay += wv[j] * bf2f((unsigned short)(g[j].x >> 16));
                az += wv[j] * bf2f((unsigned short)(g[j].y & 0xffffu));
                aw += wv[j] * bf2f((unsigned short)(g[j].y >> 16));
            }
        }
        for (; i < nb; ++i) {
            unsigned u = __shfl(ce, i, 32);
            float w = __half2float(__ushort_as_half((unsigned short)(u >> 16)));
            uint2 g = *(const uint2*)&hb[((size_t)(u & 0xffffu) << 7) + (l32 << 2)];
            ax += w * bf2f((unsigned short)(g.x & 0xffffu));
            ay += w * bf2f((unsigned short)(g.x >> 16));
            az += w * bf2f((unsigned short)(g.y & 0xffffu));
            aw += w * bf2f((unsigned short)(g.y >> 16));
        }
        e += nb;
    }
    float4 o; o.x = ax; o.y = ay; o.z = az; o.w = aw;
    ((float4*)sup)[(size_t)node * 32 + l32] = o;
}

// ---------------- input GEMM (split-bf16, fp32-grade): 32-row tiles -------
// out = relu(x@W_in + b) -> hA, h0 copy, hbf mirror. 80KB LDS -> 2 blocks/CU.

__global__ __launch_bounds__(256)
void gemm_in(const float* __restrict__ inA,
             const unsigned short* __restrict__ Bhi,
             const unsigned short* __restrict__ Blo,
             const float* __restrict__ bias,
             float* __restrict__ out, float* __restrict__ out2,
             unsigned short* __restrict__ outbf, int M) {
    extern __shared__ char lds[];
    char* Ahi = lds;                 // 32*128 bf16 = 8KB
    char* Alo = Ahi + 8192;          // 8KB
    char* Whi = Alo + 8192;          // 32KB
    char* Wlo = Whi + 32768;         // 32KB

    const int tid  = threadIdx.x;
    const int row0 = blockIdx.x * 32;

    for (int c = tid; c < 512; c += 256) {             // 32 rows x 16 chunks
        int row = c >> 4, k8 = c & 15;
        int grow = row0 + row;
        short8 hv = {0,0,0,0,0,0,0,0};
        short8 lv = {0,0,0,0,0,0,0,0};
        if (grow < M) {
            const float* s = &inA[(size_t)grow * 128 + k8 * 8];
            float4 f0 = *(const float4*)s;
            float4 f1 = *(const float4*)(s + 4);
            float ff[8] = {f0.x, f0.y, f0.z, f0.w, f1.x, f1.y, f1.z, f1.w};
            #pragma unroll
            for (int j = 0; j < 8; ++j) {
                unsigned short hh = f2bf(ff[j]);
                hv[j] = (short)hh;
                lv[j] = (short)f2bf(ff[j] - bf2f(hh));
            }
        }
        int off = row * 256 + ((k8 ^ (row & 7)) << 4);
        *(short8*)(Ahi + off) = hv;
        *(short8*)(Alo + off) = lv;
    }
    for (int c = tid; c < 2048; c += 256) {            // 128 n-rows x 16 chunks
        int n = c >> 4, k8 = c & 15;
        int off = n * 256 + ((k8 ^ (n & 7)) << 4);
        *(short8*)(Whi + off) = *(const short8*)&Bhi[n * 128 + k8 * 8];
        *(short8*)(Wlo + off) = *(const short8*)&Blo[n * 128 + k8 * 8];
    }
    __syncthreads();

    const int lane = tid & 63;
    const int w    = tid >> 6;        // wave 0..3 -> cols w*32..w*32+31
    const int lr   = lane & 15;
    const int lg   = lane >> 4;

    f32x4 acc[2][2];
    #pragma unroll
    for (int m = 0; m < 2; ++m)
        #pragma unroll
        for (int n2 = 0; n2 < 2; ++n2) acc[m][n2] = (f32x4){0.f, 0.f, 0.f, 0.f};

    #pragma unroll
    for (int kk = 0; kk < 4; ++kk) {
        int k8 = kk * 4 + lg;
        short8 a[2], al[2], b[2], bl[2];
        #pragma unroll
        for (int m = 0; m < 2; ++m) {
            int row = m * 16 + lr;
            int off = row * 256 + ((k8 ^ (row & 7)) << 4);
            a[m]  = *(const short8*)(Ahi + off);
            al[m] = *(const short8*)(Alo + off);
        }
        #pragma unroll
        for (int n2 = 0; n2 < 2; ++n2) {
            int n = (w * 2 + n2) * 16 + lr;
            int off = n * 256 + ((k8 ^ (n & 7)) << 4);
            b[n2]  = *(const short8*)(Whi + off);
            bl[n2] = *(const short8*)(Wlo + off);
        }
        #pragma unroll
        for (int m = 0; m < 2; ++m)
            #pragma unroll
            for (int n2 = 0; n2 < 2; ++n2) {
                acc[m][n2] = __builtin_amdgcn_mfma_f32_16x16x32_bf16(al[m], b[n2], acc[m][n2], 0, 0, 0);
                acc[m][n2] = __builtin_amdgcn_mfma_f32_16x16x32_bf16(a[m], bl[n2], acc[m][n2], 0, 0, 0);
                acc[m][n2] = __builtin_amdgcn_mfma_f32_16x16x32_bf16(a[m], b[n2], acc[m][n2], 0, 0, 0);
            }
    }

    #pragma unroll
    for (int m = 0; m < 2; ++m) {
        #pragma unroll
        for (int n2 = 0; n2 < 2; ++n2) {
            int col = (w * 2 + n2) * 16 + lr;
            #pragma unroll
            for (int r = 0; r < 4; ++r) {
                int row = row0 + m * 16 + lg * 4 + r;
                if (row < M) {
                    float o = fmaxf(acc[m][n2][r] + bias[col], 0.f);
                    out [(size_t)row * 128 + col] = o;
                    out2[(size_t)row * 128 + col] = o;
                    outbf[(size_t)row * 128 + col] = f2bf(o);
                }
            }
        }
    }
}

// ---------------- layer GEMM: relu(beta*(sup@W) + (1-beta)*sup) -----------
// 64-row tile, 48KB LDS -> 3 blocks/CU. bf16 A (rounded in staging), bf16 W.

__global__ __launch_bounds__(256)
void gemm_layer(const float* __restrict__ inA,
                const unsigned short* __restrict__ Bhi,
                float beta, float gamma,
                float* __restrict__ out,
                unsigned short* __restrict__ outbf, int M) {
    extern __shared__ char lds[];
    char* Ahi = lds;                 // 64*128 bf16 = 16KB
    char* Whi = Ahi + 16384;         // 32KB

    const int tid  = threadIdx.x;
    const int row0 = blockIdx.x * 64;

    for (int c = tid; c < 1024; c += 256) {            // 64 rows x 16 chunks
        int row = c >> 4, k8 = c & 15;
        int grow = row0 + row;
        short8 hv = {0,0,0,0,0,0,0,0};
        if (grow < M) {
            const float* s = &inA[(size_t)grow * 128 + k8 * 8];
            float4 f0 = *(const float4*)s;
            float4 f1 = *(const float4*)(s + 4);
            float ff[8] = {f0.x, f0.y, f0.z, f0.w, f1.x, f1.y, f1.z, f1.w};
            #pragma unroll
            for (int j = 0; j < 8; ++j) hv[j] = (short)f2bf(ff[j]);
        }
        int off = row * 256 + ((k8 ^ (row & 7)) << 4);
        *(short8*)(Ahi + off) = hv;
    }
    for (int c = tid; c < 2048; c += 256) {
        int n = c >> 4, k8 = c & 15;
        int off = n * 256 + ((k8 ^ (n & 7)) << 4);
        *(short8*)(Whi + off) = *(const short8*)&Bhi[n * 128 + k8 * 8];
    }
    __syncthreads();

    const int lane = tid & 63;
    const int w    = tid >> 6;
    const int lr   = lane & 15;
    const int lg   = lane >> 4;

    f32x4 acc[4][2];
    #pragma unroll
    for (int m = 0; m < 4; ++m)
        #pragma unroll
        for (int n2 = 0; n2 < 2; ++n2) acc[m][n2] = (f32x4){0.f, 0.f, 0.f, 0.f};

    #pragma unroll
    for (int kk = 0; kk < 4; ++kk) {
        int k8 = kk * 4 + lg;
        short8 a[4], b[2];
        #pragma unroll
        for (int m = 0; m < 4; ++m) {
            int row = m * 16 + lr;
            a[m] = *(const short8*)(Ahi + row * 256 + ((k8 ^ (row & 7)) << 4));
        }
        #pragma unroll
        for (int n2 = 0; n2 < 2; ++n2) {
            int n = (w * 2 + n2) * 16 + lr;
            b[n2] = *(const short8*)(Whi + n * 256 + ((k8 ^ (n & 7)) << 4));
        }
        #pragma unroll
        for (int m = 0; m < 4; ++m)
            #pragma unroll
            for (int n2 = 0; n2 < 2; ++n2)
                acc[m][n2] = __builtin_amdgcn_mfma_f32_16x16x32_bf16(a[m], b[n2], acc[m][n2], 0, 0, 0);
    }

    #pragma unroll
    for (int m = 0; m < 4; ++m) {
        #pragma unroll
        for (int n2 = 0; n2 < 2; ++n2) {
            int col = (w * 2 + n2) * 16 + lr;
            #pragma unroll
            for (int r = 0; r < 4; ++r) {
                int row = row0 + m * 16 + lg * 4 + r;
                if (row < M) {
                    float o = beta * acc[m][n2][r]
                            + gamma * inA[(size_t)row * 128 + col];
                    o = fmaxf(o, 0.f);
                    out[(size_t)row * 128 + col] = o;
                    if (outbf) outbf[(size_t)row * 128 + col] = f2bf(o);
                }
            }
        }
    }
}

// ---------------- output GEMM: [M,128] @ [128,40] + b (fp32) --------------

__global__ __launch_bounds__(320)
void k_out(const float* __restrict__ h, const float* __restrict__ W,
           const float* __restrict__ b, float* __restrict__ out, int M, int C) {
    __shared__ float Ws[128 * 41];
    __shared__ float xs[32 * 132];
    const int tid  = threadIdx.x;    // 320
    const int row0 = blockIdx.x * 32;

    for (int i = tid; i < 128 * 40; i += 320) {
        int k = i / 40, c = i % 40;
        Ws[k * 41 + c] = W[i];
    }
    {
        const float4* h4 = (const float4*)h;
        for (int i = tid; i < 1024; i += 320) {
            int r = i >> 5, c4 = i & 31;
            int gr = row0 + r;
            float4 v = make_float4(0.f, 0.f, 0.f, 0.f);
            if (gr < M) v = h4[(size_t)gr * 32 + c4];
            *(float4*)&xs[r * 132 + c4 * 4] = v;
        }
    }
    __syncthreads();

    const int c  = tid % 40;
    const int rg = tid / 40;
    float acc[4] = {0.f, 0.f, 0.f, 0.f};
    #pragma unroll 4
    for (int k4 = 0; k4 < 32; ++k4) {
        float w0 = Ws[(k4 * 4 + 0) * 41 + c];
        float w1 = Ws[(k4 * 4 + 1) * 41 + c];
        float w2 = Ws[(k4 * 4 + 2) * 41 + c];
        float w3 = Ws[(k4 * 4 + 3) * 41 + c];
        #pragma unroll
        for (int i = 0; i < 4; ++i) {
            float4 x = *(const float4*)&xs[(rg * 4 + i) * 132 + k4 * 4];
            acc[i] += x.x * w0 + x.y * w1 + x.z * w2 + x.w * w3;
        }
    }
    float bb = b[c];
    #pragma unroll
    for (int i = 0; i < 4; ++i) {
        int r = row0 + rg * 4 + i;
        if (r < M) out[(size_t)r * C + c] = acc[i] + bb;
    }
}

// ---------------- host ----------------

extern "C" void kernel_launch(void* const* d_in, const int* in_sizes, int n_in,
                              void* d_out, int out_size, void* d_ws, size_t ws_size,
                              hipStream_t stream) {
    const float* x        = (const float*)d_in[0];
    const int*   ei       = (const int*)d_in[1];
    const float* W_in     = (const float*)d_in[2];
    const float* b_in     = (const float*)d_in[3];
    const float* W_layers = (const float*)d_in[4];
    const float* W_out    = (const float*)d_in[5];
    const float* b_out    = (const float*)d_in[6];
    float* out = (float*)d_out;

    const int H = 128;
    const int N = in_sizes[0] / H;             // 50000 (must be < 65536 for packed CSR)
    const int E = in_sizes[1] / 2;             // 800000
    const int L = in_sizes[4] / (H * H);       // 4
    const int C = in_sizes[5] / H;             // 40

    char* p = (char*)d_ws;
    auto alloc = [&](size_t bytes) {
        char* r = p;
        p += (bytes + 255) & ~(size_t)255;
        return r;
    };
    int*      cnt   = (int*)alloc((size_t)N * 4);
    int*      offs  = (int*)alloc((size_t)(N + 1) * 4);
    int*      parts = (int*)alloc(256 * 4);
    unsigned* csr   = (unsigned*)alloc((size_t)E * 4);
    float*    dinv  = (float*)alloc((size_t)N * 4);
    float*    h0    = (float*)alloc((size_t)N * H * 4);
    float*    hA    = (float*)alloc((size_t)N * H * 4);
    float*    hB    = (float*)alloc((size_t)N * H * 4);
    unsigned short* hbf = (unsigned short*)alloc((size_t)N * H * 2);
    unsigned short* wt  = (unsigned short*)alloc((size_t)L * H * H * 2);
    unsigned short* wht = (unsigned short*)alloc((size_t)H * H * 2);
    unsigned short* wlt = (unsigned short*)alloc((size_t)H * H * 2);
    (void)ws_size;

    const int* ei0 = ei;        // destinations (row)
    const int* ei1 = ei + E;    // sources (col)

    const int nblkN = (N + 255) / 256;
    const int nblkE = (E + 255) / 256;

    k_wprep<<<5, 256, 0, stream>>>(W_layers, W_in, wt, wht, wlt);

    hipMemsetAsync(cnt, 0, (size_t)N * 4, stream);
    k_count<<<nblkE, 256, 0, stream>>>(ei0, cnt, E);
    k_dinv<<<nblkN, 256, 0, stream>>>(cnt, dinv, N);
    k_scan_part<<<nblkN, 256, 0, stream>>>(cnt, offs, parts, N);
    k_scan_tops<<<1, 256, 0, stream>>>(parts, nblkN);
    k_scan_add<<<nblkN, 256, 0, stream>>>(offs, parts, N, E);
    hipMemsetAsync(cnt, 0, (size_t)N * 4, stream);
    k_scatter<<<nblkE, 256, 0, stream>>>(ei0, ei1, offs, cnt, dinv, csr, E);

    // input linear (split-bf16, fp32-grade) + relu -> hA, h0, hbf
    gemm_in<<<(N + 31) / 32, 256, 80 * 1024, stream>>>(
        x, wht, wlt, b_in, hA, h0, hbf, N);

    for (int l = 0; l < L; ++l) {
        float beta = logf(0.5f / (float)(l + 1) + 1.0f);
        k_spmm<<<(N + 7) / 8, 256, 0, stream>>>(offs, csr, hA, hbf, h0, dinv, hB, N, E);
        gemm_layer<<<(N + 63) / 64, 256, 48 * 1024, stream>>>(
            hB, wt + (size_t)l * H * H, beta, 1.0f - beta,
            hA, (l < L - 1) ? hbf : nullptr, N);
    }

    k_out<<<(N + 31) / 32, 320, 0, stream>>>(hA, W_out, b_out, out, N, C);
}

// Round 8
// 343.157 us; speedup vs baseline: 2.6180x; 1.1649x over previous
//
#include <hip/hip_runtime.h>
#include <hip/hip_bf16.h>
#include <hip/hip_fp16.h>
#include <math.h>

typedef short short8 __attribute__((ext_vector_type(8)));
typedef _Float16 half8 __attribute__((ext_vector_type(8)));
typedef float f32x4  __attribute__((ext_vector_type(4)));

__device__ __forceinline__ unsigned short f2bf(float f) {
    union { float f; unsigned u; } v; v.f = f;
    unsigned r = (v.u + 0x7FFFu + ((v.u >> 16) & 1u)) >> 16;
    return (unsigned short)r;
}
__device__ __forceinline__ float bf2f(unsigned short b) {
    union { unsigned u; float f; } v; v.u = ((unsigned)b) << 16; return v.f;
}
__device__ __forceinline__ unsigned short f2h(float f) {
    return __half_as_ushort(__float2half(f));
}
__device__ __forceinline__ float h2f(unsigned short u) {
    return __half2float(__ushort_as_half(u));
}

// ---------------- CSR build ----------------

__global__ void k_count(const int* __restrict__ dst, int* __restrict__ cnt, int E) {
    int e = blockIdx.x * 256 + threadIdx.x;
    if (e < E) atomicAdd(&cnt[dst[e]], 1);
}

__global__ void k_dinv(const int* __restrict__ cnt, float* __restrict__ dinv, int n) {
    int i = blockIdx.x * 256 + threadIdx.x;
    if (i < n) dinv[i] = 1.0f / sqrtf((float)cnt[i] + 1.0f);  // +1 self-loop
}

__global__ void k_scan_part(const int* __restrict__ cnt, int* __restrict__ offs,
                            int* __restrict__ parts, int n) {
    __shared__ int s[256];
    int i = blockIdx.x * 256 + threadIdx.x;
    int v = (i < n) ? cnt[i] : 0;
    s[threadIdx.x] = v;
    __syncthreads();
    #pragma unroll
    for (int d = 1; d < 256; d <<= 1) {
        int t = (threadIdx.x >= d) ? s[threadIdx.x - d] : 0;
        __syncthreads();
        s[threadIdx.x] += t;
        __syncthreads();
    }
    if (i < n) offs[i] = s[threadIdx.x] - v;        // block-local exclusive
    if (threadIdx.x == 255) parts[blockIdx.x] = s[255];
}

__global__ void k_scan_tops(int* __restrict__ parts, int np) {
    __shared__ int s[256];
    int tid = threadIdx.x;
    int v = (tid < np) ? parts[tid] : 0;
    s[tid] = v;
    __syncthreads();
    #pragma unroll
    for (int d = 1; d < 256; d <<= 1) {
        int t = (tid >= d) ? s[tid - d] : 0;
        __syncthreads();
        s[tid] += t;
        __syncthreads();
    }
    if (tid < np) parts[tid] = s[tid] - v;          // exclusive
}

__global__ void k_scan_add(int* __restrict__ offs, const int* __restrict__ parts,
                           int n, int e_total) {
    int i = blockIdx.x * 256 + threadIdx.x;
    if (i < n) offs[i] += parts[blockIdx.x];
    if (blockIdx.x == 0 && threadIdx.x == 0) offs[n] = e_total;
}

// csr entry (4B) = fp16(0.9*dinv[d]*dinv[s]) << 16 | src   (src < 65536)
__global__ void k_scatter(const int* __restrict__ dst, const int* __restrict__ src,
                          const int* __restrict__ offs, int* __restrict__ cur,
                          const float* __restrict__ dinv, unsigned* __restrict__ csr, int E) {
    int e = blockIdx.x * 256 + threadIdx.x;
    if (e < E) {
        int d = dst[e], s = src[e];
        int pos = offs[d] + atomicAdd(&cur[d], 1);
        float w = 0.9f * dinv[d] * dinv[s];
        unsigned hw = (unsigned)f2h(w);
        csr[pos] = (hw << 16) | (unsigned)s;
    }
}

// ---------------- weight prep ----------------
// blockIdx 0..3: wt (fp16)  [l][n][k] = W_layers[l][k][n]
// blockIdx 4   : wht/wlt (bf16 split) [n][k] of W_in

__global__ void k_wprep(const float* __restrict__ Wl, const float* __restrict__ Win,
                        unsigned short* __restrict__ wt,
                        unsigned short* __restrict__ wht,
                        unsigned short* __restrict__ wlt) {
    int m = blockIdx.x;
    for (int i = threadIdx.x; i < 16384; i += 256) {
        int n = i >> 7, k = i & 127;
        if (m < 4) {
            wt[m * 16384 + n * 128 + k] = f2h(Wl[m * 16384 + k * 128 + n]);
        } else {
            float f = Win[k * 128 + n];
            unsigned short h = f2bf(f);
            wht[n * 128 + k] = h;
            wlt[n * 128 + k] = f2bf(f - bf2f(h));
        }
    }
}

// ---------------- SpMM: supb = fp16(0.9*A_hat*h + 0.1*h0) ----------------
// HALF-WAVE per node. All state fp16 (hb, h0b, supb); fp32 accumulation.
// Each lane owns 4 features (8B gather) -> one load services TWO edges.

__global__ __launch_bounds__(256)
void k_spmm(const int* __restrict__ offs, const unsigned* __restrict__ csr,
            const unsigned short* __restrict__ hb,
            const unsigned short* __restrict__ h0b,
            const float* __restrict__ dinv,
            unsigned short* __restrict__ supb, int n, int E) {
    int node = blockIdx.x * 8 + (threadIdx.x >> 5);
    if (node >= n) return;
    int l32 = threadIdx.x & 31;
    float di = dinv[node];
    float ws = 0.9f * di * di;
    uint2 sv = *(const uint2*)&hb [((size_t)node << 7) + (l32 << 2)];
    uint2 rv = *(const uint2*)&h0b[((size_t)node << 7) + (l32 << 2)];
    float ax = ws * h2f((unsigned short)(sv.x & 0xffffu)) + 0.1f * h2f((unsigned short)(rv.x & 0xffffu));
    float ay = ws * h2f((unsigned short)(sv.x >> 16))     + 0.1f * h2f((unsigned short)(rv.x >> 16));
    float az = ws * h2f((unsigned short)(sv.y & 0xffffu)) + 0.1f * h2f((unsigned short)(rv.y & 0xffffu));
    float aw = ws * h2f((unsigned short)(sv.y >> 16))     + 0.1f * h2f((unsigned short)(rv.y >> 16));
    int e = offs[node], end = offs[node + 1];
    while (e < end) {
        int nb = end - e;
        if (nb > 32) nb = 32;
        unsigned ce = csr[min(e + l32, E - 1)];   // coalesced 128B per half
        int i = 0;
        for (; i + 8 <= nb; i += 8) {
            uint2 g[8]; float wv[8];
            #pragma unroll
            for (int j = 0; j < 8; ++j) {
                unsigned u = __shfl(ce, i + j, 32);
                wv[j] = h2f((unsigned short)(u >> 16));
                g[j] = *(const uint2*)&hb[((size_t)(u & 0xffffu) << 7) + (l32 << 2)];
            }
            #pragma unroll
            for (int j = 0; j < 8; ++j) {
                ax += wv[j] * h2f((unsigned short)(g[j].x & 0xffffu));
                ay += wv[j] * h2f((unsigned short)(g[j].x >> 16));
                az += wv[j] * h2f((unsigned short)(g[j].y & 0xffffu));
                aw += wv[j] * h2f((unsigned short)(g[j].y >> 16));
            }
        }
        for (; i + 4 <= nb; i += 4) {
            uint2 g[4]; float wv[4];
            #pragma unroll
            for (int j = 0; j < 4; ++j) {
                unsigned u = __shfl(ce, i + j, 32);
                wv[j] = h2f((unsigned short)(u >> 16));
                g[j] = *(const uint2*)&hb[((size_t)(u & 0xffffu) << 7) + (l32 << 2)];
            }
            #pragma unroll
            for (int j = 0; j < 4; ++j) {
                ax += wv[j] * h2f((unsigned short)(g[j].x & 0xffffu));
                ay += wv[j] * h2f((unsigned short)(g[j].x >> 16));
                az += wv[j] * h2f((unsigned short)(g[j].y & 0xffffu));
                aw += wv[j] * h2f((unsigned short)(g[j].y >> 16));
            }
        }
        for (; i + 2 <= nb; i += 2) {
            uint2 g[2]; float wv[2];
            #pragma unroll
            for (int j = 0; j < 2; ++j) {
                unsigned u = __shfl(ce, i + j, 32);
                wv[j] = h2f((unsigned short)(u >> 16));
                g[j] = *(const uint2*)&hb[((size_t)(u & 0xffffu) << 7) + (l32 << 2)];
            }
            #pragma unroll
            for (int j = 0; j < 2; ++j) {
                ax += wv[j] * h2f((unsigned short)(g[j].x & 0xffffu));
                ay += wv[j] * h2f((unsigned short)(g[j].x >> 16));
                az += wv[j] * h2f((unsigned short)(g[j].y & 0xffffu));
                aw += wv[j] * h2f((unsigned short)(g[j].y >> 16));
            }
        }
        for (; i < nb; ++i) {
            unsigned u = __shfl(ce, i, 32);
            float w = h2f((unsigned short)(u >> 16));
            uint2 g = *(const uint2*)&hb[((size_t)(u & 0xffffu) << 7) + (l32 << 2)];
            ax += w * h2f((unsigned short)(g.x & 0xffffu));
            ay += w * h2f((unsigned short)(g.x >> 16));
            az += w * h2f((unsigned short)(g.y & 0xffffu));
            aw += w * h2f((unsigned short)(g.y >> 16));
        }
        e += nb;
    }
    uint2 o;
    o.x = (unsigned)f2h(ax) | ((unsigned)f2h(ay) << 16);
    o.y = (unsigned)f2h(az) | ((unsigned)f2h(aw) << 16);
    *(uint2*)&supb[((size_t)node << 7) + (l32 << 2)] = o;
}

// ---------------- input GEMM (split-bf16, fp32-grade): 32-row tiles -------
// out = relu(x@W_in + b) -> hb (fp16), h0b (fp16). 80KB LDS -> 2 blocks/CU.

__global__ __launch_bounds__(256)
void gemm_in(const float* __restrict__ inA,
             const unsigned short* __restrict__ Bhi,
             const unsigned short* __restrict__ Blo,
             const float* __restrict__ bias,
             unsigned short* __restrict__ hb,
             unsigned short* __restrict__ h0b, int M) {
    extern __shared__ char lds[];
    char* Ahi = lds;                 // 32*128 bf16 = 8KB
    char* Alo = Ahi + 8192;          // 8KB
    char* Whi = Alo + 8192;          // 32KB
    char* Wlo = Whi + 32768;         // 32KB

    const int tid  = threadIdx.x;
    const int row0 = blockIdx.x * 32;

    for (int c = tid; c < 512; c += 256) {             // 32 rows x 16 chunks
        int row = c >> 4, k8 = c & 15;
        int grow = row0 + row;
        short8 hv = {0,0,0,0,0,0,0,0};
        short8 lv = {0,0,0,0,0,0,0,0};
        if (grow < M) {
            const float* s = &inA[(size_t)grow * 128 + k8 * 8];
            float4 f0 = *(const float4*)s;
            float4 f1 = *(const float4*)(s + 4);
            float ff[8] = {f0.x, f0.y, f0.z, f0.w, f1.x, f1.y, f1.z, f1.w};
            #pragma unroll
            for (int j = 0; j < 8; ++j) {
                unsigned short hh = f2bf(ff[j]);
                hv[j] = (short)hh;
                lv[j] = (short)f2bf(ff[j] - bf2f(hh));
            }
        }
        int off = row * 256 + ((k8 ^ (row & 7)) << 4);
        *(short8*)(Ahi + off) = hv;
        *(short8*)(Alo + off) = lv;
    }
    for (int c = tid; c < 2048; c += 256) {            // 128 n-rows x 16 chunks
        int n = c >> 4, k8 = c & 15;
        int off = n * 256 + ((k8 ^ (n & 7)) << 4);
        *(short8*)(Whi + off) = *(const short8*)&Bhi[n * 128 + k8 * 8];
        *(short8*)(Wlo + off) = *(const short8*)&Blo[n * 128 + k8 * 8];
    }
    __syncthreads();

    const int lane = tid & 63;
    const int w    = tid >> 6;        // wave 0..3 -> cols w*32..w*32+31
    const int lr   = lane & 15;
    const int lg   = lane >> 4;

    f32x4 acc[2][2];
    #pragma unroll
    for (int m = 0; m < 2; ++m)
        #pragma unroll
        for (int n2 = 0; n2 < 2; ++n2) acc[m][n2] = (f32x4){0.f, 0.f, 0.f, 0.f};

    #pragma unroll
    for (int kk = 0; kk < 4; ++kk) {
        int k8 = kk * 4 + lg;
        short8 a[2], al[2], b[2], bl[2];
        #pragma unroll
        for (int m = 0; m < 2; ++m) {
            int row = m * 16 + lr;
            int off = row * 256 + ((k8 ^ (row & 7)) << 4);
            a[m]  = *(const short8*)(Ahi + off);
            al[m] = *(const short8*)(Alo + off);
        }
        #pragma unroll
        for (int n2 = 0; n2 < 2; ++n2) {
            int n = (w * 2 + n2) * 16 + lr;
            int off = n * 256 + ((k8 ^ (n & 7)) << 4);
            b[n2]  = *(const short8*)(Whi + off);
            bl[n2] = *(const short8*)(Wlo + off);
        }
        #pragma unroll
        for (int m = 0; m < 2; ++m)
            #pragma unroll
            for (int n2 = 0; n2 < 2; ++n2) {
                acc[m][n2] = __builtin_amdgcn_mfma_f32_16x16x32_bf16(al[m], b[n2], acc[m][n2], 0, 0, 0);
                acc[m][n2] = __builtin_amdgcn_mfma_f32_16x16x32_bf16(a[m], bl[n2], acc[m][n2], 0, 0, 0);
                acc[m][n2] = __builtin_amdgcn_mfma_f32_16x16x32_bf16(a[m], b[n2], acc[m][n2], 0, 0, 0);
            }
    }

    #pragma unroll
    for (int m = 0; m < 2; ++m) {
        #pragma unroll
        for (int n2 = 0; n2 < 2; ++n2) {
            int col = (w * 2 + n2) * 16 + lr;
            #pragma unroll
            for (int r = 0; r < 4; ++r) {
                int row = row0 + m * 16 + lg * 4 + r;
                if (row < M) {
                    float o = fmaxf(acc[m][n2][r] + bias[col], 0.f);
                    unsigned short ob = f2h(o);
                    hb [(size_t)row * 128 + col] = ob;
                    h0b[(size_t)row * 128 + col] = ob;
                }
            }
        }
    }
}

// ---------------- layer GEMM: relu(beta*(sup@W) + (1-beta)*sup) -----------
// A = fp16 sup (staged direct), W fp16, f16 MFMA, residual read from the
// staged LDS tile (no second global read). LAST: write fp32 hA for k_out;
// else write fp16 hb. 48KB LDS -> 3 blocks/CU.

template<int LAST>
__global__ __launch_bounds__(256)
void gemm_layer(const unsigned short* __restrict__ supb,
                const unsigned short* __restrict__ Bh,
                float beta, float gamma,
                float* __restrict__ outf,
                unsigned short* __restrict__ outh, int M) {
    extern __shared__ char lds[];
    char* Ah = lds;                  // 64*128 fp16 = 16KB
    char* Wh = Ah + 16384;           // 32KB

    const int tid  = threadIdx.x;
    const int row0 = blockIdx.x * 64;

    for (int c = tid; c < 1024; c += 256) {            // 64 rows x 16 chunks
        int row = c >> 4, k8 = c & 15;
        int grow = row0 + row;
        short8 hv = {0,0,0,0,0,0,0,0};
        if (grow < M) hv = *(const short8*)&supb[(size_t)grow * 128 + k8 * 8];
        *(short8*)(Ah + row * 256 + ((k8 ^ (row & 7)) << 4)) = hv;
    }
    for (int c = tid; c < 2048; c += 256) {
        int n = c >> 4, k8 = c & 15;
        *(short8*)(Wh + n * 256 + ((k8 ^ (n & 7)) << 4)) = *(const short8*)&Bh[n * 128 + k8 * 8];
    }
    __syncthreads();

    const int lane = tid & 63;
    const int w    = tid >> 6;
    const int lr   = lane & 15;
    const int lg   = lane >> 4;

    f32x4 acc[4][2];
    #pragma unroll
    for (int m = 0; m < 4; ++m)
        #pragma unroll
        for (int n2 = 0; n2 < 2; ++n2) acc[m][n2] = (f32x4){0.f, 0.f, 0.f, 0.f};

    #pragma unroll
    for (int kk = 0; kk < 4; ++kk) {
        int k8 = kk * 4 + lg;
        half8 a[4], b[2];
        #pragma unroll
        for (int m = 0; m < 4; ++m) {
            int row = m * 16 + lr;
            a[m] = *(const half8*)(Ah + row * 256 + ((k8 ^ (row & 7)) << 4));
        }
        #pragma unroll
        for (int n2 = 0; n2 < 2; ++n2) {
            int n = (w * 2 + n2) * 16 + lr;
            b[n2] = *(const half8*)(Wh + n * 256 + ((k8 ^ (n & 7)) << 4));
        }
        #pragma unroll
        for (int m = 0; m < 4; ++m)
            #pragma unroll
            for (int n2 = 0; n2 < 2; ++n2)
                acc[m][n2] = __builtin_amdgcn_mfma_f32_16x16x32_f16(a[m], b[n2], acc[m][n2], 0, 0, 0);
    }

    #pragma unroll
    for (int m = 0; m < 4; ++m) {
        #pragma unroll
        for (int n2 = 0; n2 < 2; ++n2) {
            int col = (w * 2 + n2) * 16 + lr;
            int k8c = col >> 3;
            int ebc = (col & 7) * 2;
            #pragma unroll
            for (int r = 0; r < 4; ++r) {
                int rl  = m * 16 + lg * 4 + r;
                int row = row0 + rl;
                if (row < M) {
                    // residual from the staged fp16 tile in LDS
                    unsigned short rb = *(const unsigned short*)
                        (Ah + rl * 256 + ((k8c ^ (rl & 7)) << 4) + ebc);
                    float o = beta * acc[m][n2][r] + gamma * h2f(rb);
                    o = fmaxf(o, 0.f);
                    if (LAST) outf[(size_t)row * 128 + col] = o;
                    else      outh[(size_t)row * 128 + col] = f2h(o);
                }
            }
        }
    }
}

// ---------------- output GEMM: [M,128] @ [128,40] + b (fp32) --------------

__global__ __launch_bounds__(320)
void k_out(const float* __restrict__ h, const float* __restrict__ W,
           const float* __restrict__ b, float* __restrict__ out, int M, int C) {
    __shared__ float Ws[128 * 41];
    __shared__ float xs[32 * 132];
    const int tid  = threadIdx.x;    // 320
    const int row0 = blockIdx.x * 32;

    for (int i = tid; i < 128 * 40; i += 320) {
        int k = i / 40, c = i % 40;
        Ws[k * 41 + c] = W[i];
    }
    {
        const float4* h4 = (const float4*)h;
        for (int i = tid; i < 1024; i += 320) {
            int r = i >> 5, c4 = i & 31;
            int gr = row0 + r;
            float4 v = make_float4(0.f, 0.f, 0.f, 0.f);
            if (gr < M) v = h4[(size_t)gr * 32 + c4];
            *(float4*)&xs[r * 132 + c4 * 4] = v;
        }
    }
    __syncthreads();

    const int c  = tid % 40;
    const int rg = tid / 40;
    float acc[4] = {0.f, 0.f, 0.f, 0.f};
    #pragma unroll 4
    for (int k4 = 0; k4 < 32; ++k4) {
        float w0 = Ws[(k4 * 4 + 0) * 41 + c];
        float w1 = Ws[(k4 * 4 + 1) * 41 + c];
        float w2 = Ws[(k4 * 4 + 2) * 41 + c];
        float w3 = Ws[(k4 * 4 + 3) * 41 + c];
        #pragma unroll
        for (int i = 0; i < 4; ++i) {
            float4 x = *(const float4*)&xs[(rg * 4 + i) * 132 + k4 * 4];
            acc[i] += x.x * w0 + x.y * w1 + x.z * w2 + x.w * w3;
        }
    }
    float bb = b[c];
    #pragma unroll
    for (int i = 0; i < 4; ++i) {
        int r = row0 + rg * 4 + i;
        if (r < M) out[(size_t)r * C + c] = acc[i] + bb;
    }
}

// ---------------- host ----------------

extern "C" void kernel_launch(void* const* d_in, const int* in_sizes, int n_in,
                              void* d_out, int out_size, void* d_ws, size_t ws_size,
                              hipStream_t stream) {
    const float* x        = (const float*)d_in[0];
    const int*   ei       = (const int*)d_in[1];
    const float* W_in     = (const float*)d_in[2];
    const float* b_in     = (const float*)d_in[3];
    const float* W_layers = (const float*)d_in[4];
    const float* W_out    = (const float*)d_in[5];
    const float* b_out    = (const float*)d_in[6];
    float* out = (float*)d_out;

    const int H = 128;
    const int N = in_sizes[0] / H;             // 50000 (< 65536 for packed CSR)
    const int E = in_sizes[1] / 2;             // 800000
    const int L = in_sizes[4] / (H * H);       // 4
    const int C = in_sizes[5] / H;             // 40

    char* p = (char*)d_ws;
    auto alloc = [&](size_t bytes) {
        char* r = p;
        p += (bytes + 255) & ~(size_t)255;
        return r;
    };
    int*      cnt   = (int*)alloc((size_t)N * 4);
    int*      offs  = (int*)alloc((size_t)(N + 1) * 4);
    int*      parts = (int*)alloc(256 * 4);
    unsigned* csr   = (unsigned*)alloc((size_t)E * 4);
    float*    dinv  = (float*)alloc((size_t)N * 4);
    float*    hA    = (float*)alloc((size_t)N * H * 4);   // last-layer fp32 h
    unsigned short* hb   = (unsigned short*)alloc((size_t)N * H * 2);
    unsigned short* h0b  = (unsigned short*)alloc((size_t)N * H * 2);
    unsigned short* supb = (unsigned short*)alloc((size_t)N * H * 2);
    unsigned short* wt   = (unsigned short*)alloc((size_t)L * H * H * 2);
    unsigned short* wht  = (unsigned short*)alloc((size_t)H * H * 2);
    unsigned short* wlt  = (unsigned short*)alloc((size_t)H * H * 2);
    (void)ws_size;

    const int* ei0 = ei;        // destinations (row)
    const int* ei1 = ei + E;    // sources (col)

    const int nblkN = (N + 255) / 256;
    const int nblkE = (E + 255) / 256;

    k_wprep<<<5, 256, 0, stream>>>(W_layers, W_in, wt, wht, wlt);

    hipMemsetAsync(cnt, 0, (size_t)N * 4, stream);
    k_count<<<nblkE, 256, 0, stream>>>(ei0, cnt, E);
    k_dinv<<<nblkN, 256, 0, stream>>>(cnt, dinv, N);
    k_scan_part<<<nblkN, 256, 0, stream>>>(cnt, offs, parts, N);
    k_scan_tops<<<1, 256, 0, stream>>>(parts, nblkN);
    k_scan_add<<<nblkN, 256, 0, stream>>>(offs, parts, N, E);
    hipMemsetAsync(cnt, 0, (size_t)N * 4, stream);
    k_scatter<<<nblkE, 256, 0, stream>>>(ei0, ei1, offs, cnt, dinv, csr, E);

    // input linear (split-bf16, fp32-grade) + relu -> hb, h0b (fp16)
    gemm_in<<<(N + 31) / 32, 256, 80 * 1024, stream>>>(
        x, wht, wlt, b_in, hb, h0b, N);

    for (int l = 0; l < L; ++l) {
        float beta = logf(0.5f / (float)(l + 1) + 1.0f);
        k_spmm<<<(N + 7) / 8, 256, 0, stream>>>(offs, csr, hb, h0b, dinv, supb, N, E);
        if (l < L - 1)
            gemm_layer<0><<<(N + 63) / 64, 256, 48 * 1024, stream>>>(
                supb, wt + (size_t)l * H * H, beta, 1.0f - beta, nullptr, hb, N);
        else
            gemm_layer<1><<<(N + 63) / 64, 256, 48 * 1024, stream>>>(
                supb, wt + (size_t)l * H * H, beta, 1.0f - beta, hA, nullptr, N);
    }

    k_out<<<(N + 31) / 32, 320, 0, stream>>>(hA, W_out, b_out, out, N, C);
}

// Round 9
// 294.544 us; speedup vs baseline: 3.0501x; 1.1650x over previous
//
#include <hip/hip_runtime.h>
#include <hip/hip_bf16.h>
#include <hip/hip_fp16.h>
#include <math.h>

typedef short short8 __attribute__((ext_vector_type(8)));
typedef _Float16 half8 __attribute__((ext_vector_type(8)));
typedef float f32x4  __attribute__((ext_vector_type(4)));

__device__ __forceinline__ unsigned short f2h(float f) {
    return __half_as_ushort(__float2half(f));
}
__device__ __forceinline__ float h2f(unsigned short u) {
    return __half2float(__ushort_as_half(u));
}

// ---------------- CSR build ----------------
// count also records each edge's arrival rank within its destination,
// so the scatter pass needs NO atomics.

__global__ void k_count(const int* __restrict__ dst, int* __restrict__ cnt,
                        unsigned short* __restrict__ rank, int E) {
    int e = blockIdx.x * 256 + threadIdx.x;
    if (e < E) rank[e] = (unsigned short)atomicAdd(&cnt[dst[e]], 1);
}

// scan over cnt -> block-local exclusive offs (+ dinv folded in)
__global__ void k_scan_part(const int* __restrict__ cnt, int* __restrict__ offs,
                            int* __restrict__ parts, float* __restrict__ dinv, int n) {
    __shared__ int s[256];
    int i = blockIdx.x * 256 + threadIdx.x;
    int v = (i < n) ? cnt[i] : 0;
    s[threadIdx.x] = v;
    __syncthreads();
    #pragma unroll
    for (int d = 1; d < 256; d <<= 1) {
        int t = (threadIdx.x >= d) ? s[threadIdx.x - d] : 0;
        __syncthreads();
        s[threadIdx.x] += t;
        __syncthreads();
    }
    if (i < n) {
        offs[i] = s[threadIdx.x] - v;
        dinv[i] = rsqrtf((float)v + 1.0f);   // +1 self-loop
    }
    if (threadIdx.x == 255) parts[blockIdx.x] = s[255];
}

__global__ void k_scan_tops(int* __restrict__ parts, int np) {
    __shared__ int s[256];
    int tid = threadIdx.x;
    int v = (tid < np) ? parts[tid] : 0;
    s[tid] = v;
    __syncthreads();
    #pragma unroll
    for (int d = 1; d < 256; d <<= 1) {
        int t = (tid >= d) ? s[tid - d] : 0;
        __syncthreads();
        s[tid] += t;
        __syncthreads();
    }
    if (tid < np) parts[tid] = s[tid] - v;          // exclusive
}

__global__ void k_scan_add(int* __restrict__ offs, const int* __restrict__ parts,
                           int n, int e_total) {
    int i = blockIdx.x * 256 + threadIdx.x;
    if (i < n) offs[i] += parts[blockIdx.x];
    if (blockIdx.x == 0 && threadIdx.x == 0) offs[n] = e_total;
}

// csr entry (4B) = fp16(0.9*dinv[d]*dinv[s]) << 16 | src  — atomic-free
__global__ void k_scatter(const int* __restrict__ dst, const int* __restrict__ src,
                          const unsigned short* __restrict__ rank,
                          const int* __restrict__ offs,
                          const float* __restrict__ dinv,
                          unsigned* __restrict__ csr, int E) {
    int e = blockIdx.x * 256 + threadIdx.x;
    if (e < E) {
        int d = dst[e], s = src[e];
        float w = 0.9f * dinv[d] * dinv[s];
        csr[offs[d] + (int)rank[e]] = ((unsigned)f2h(w) << 16) | (unsigned)s;
    }
}

// ---------------- weight prep (all fp16, transposed) ----------------
// blk 0..3: wt[l][n][k] = W_layers[l][k][n]
// blk 4   : wint[n][k]  = W_in[k][n]
// blk 5   : wot[n][k]   = W_out[k][n] for n<40, 0-padded to 48 rows

__global__ void k_wprep(const float* __restrict__ Wl, const float* __restrict__ Win,
                        const float* __restrict__ Wout,
                        unsigned short* __restrict__ wt,
                        unsigned short* __restrict__ wint,
                        unsigned short* __restrict__ wot, int C) {
    int m = blockIdx.x;
    if (m < 4) {
        for (int i = threadIdx.x; i < 16384; i += 256) {
            int n = i >> 7, k = i & 127;
            wt[m * 16384 + n * 128 + k] = f2h(Wl[m * 16384 + k * 128 + n]);
        }
    } else if (m == 4) {
        for (int i = threadIdx.x; i < 16384; i += 256) {
            int n = i >> 7, k = i & 127;
            wint[n * 128 + k] = f2h(Win[k * 128 + n]);
        }
    } else {
        for (int i = threadIdx.x; i < 48 * 128; i += 256) {
            int n = i >> 7, k = i & 127;
            wot[n * 128 + k] = (n < C) ? f2h(Wout[k * C + n]) : (unsigned short)0;
        }
    }
}

// ---------------- SpMM: supb = fp16(0.9*A_hat*h + 0.1*h0) ----------------
// HALF-WAVE per node; lane owns 4 fp16 features (8B gather). 16/8/4/2/1
// gather tiers keep up to 16 loads in flight.

__global__ __launch_bounds__(256)
void k_spmm(const int* __restrict__ offs, const unsigned* __restrict__ csr,
            const unsigned short* __restrict__ hb,
            const unsigned short* __restrict__ h0b,
            const float* __restrict__ dinv,
            unsigned short* __restrict__ supb, int n, int E) {
    int node = blockIdx.x * 8 + (threadIdx.x >> 5);
    if (node >= n) return;
    int l32 = threadIdx.x & 31;
    float di = dinv[node];
    float ws = 0.9f * di * di;
    uint2 sv = *(const uint2*)&hb [((size_t)node << 7) + (l32 << 2)];
    uint2 rv = *(const uint2*)&h0b[((size_t)node << 7) + (l32 << 2)];
    float ax = ws * h2f((unsigned short)(sv.x & 0xffffu)) + 0.1f * h2f((unsigned short)(rv.x & 0xffffu));
    float ay = ws * h2f((unsigned short)(sv.x >> 16))     + 0.1f * h2f((unsigned short)(rv.x >> 16));
    float az = ws * h2f((unsigned short)(sv.y & 0xffffu)) + 0.1f * h2f((unsigned short)(rv.y & 0xffffu));
    float aw = ws * h2f((unsigned short)(sv.y >> 16))     + 0.1f * h2f((unsigned short)(rv.y >> 16));
    int e = offs[node], end = offs[node + 1];
    while (e < end) {
        int nb = end - e;
        if (nb > 32) nb = 32;
        unsigned ce = csr[min(e + l32, E - 1)];   // coalesced 128B per half
        int i = 0;
        for (; i + 16 <= nb; i += 16) {
            uint2 g[16]; float wv[16];
            #pragma unroll
            for (int j = 0; j < 16; ++j) {
                unsigned u = __shfl(ce, i + j, 32);
                wv[j] = h2f((unsigned short)(u >> 16));
                g[j] = *(const uint2*)&hb[((size_t)(u & 0xffffu) << 7) + (l32 << 2)];
            }
            #pragma unroll
            for (int j = 0; j < 16; ++j) {
                ax += wv[j] * h2f((unsigned short)(g[j].x & 0xffffu));
                ay += wv[j] * h2f((unsigned short)(g[j].x >> 16));
                az += wv[j] * h2f((unsigned short)(g[j].y & 0xffffu));
                aw += wv[j] * h2f((unsigned short)(g[j].y >> 16));
            }
        }
        for (; i + 8 <= nb; i += 8) {
            uint2 g[8]; float wv[8];
            #pragma unroll
            for (int j = 0; j < 8; ++j) {
                unsigned u = __shfl(ce, i + j, 32);
                wv[j] = h2f((unsigned short)(u >> 16));
                g[j] = *(const uint2*)&hb[((size_t)(u & 0xffffu) << 7) + (l32 << 2)];
            }
            #pragma unroll
            for (int j = 0; j < 8; ++j) {
                ax += wv[j] * h2f((unsigned short)(g[j].x & 0xffffu));
                ay += wv[j] * h2f((unsigned short)(g[j].x >> 16));
                az += wv[j] * h2f((unsigned short)(g[j].y & 0xffffu));
                aw += wv[j] * h2f((unsigned short)(g[j].y >> 16));
            }
        }
        for (; i + 4 <= nb; i += 4) {
            uint2 g[4]; float wv[4];
            #pragma unroll
            for (int j = 0; j < 4; ++j) {
                unsigned u = __shfl(ce, i + j, 32);
                wv[j] = h2f((unsigned short)(u >> 16));
                g[j] = *(const uint2*)&hb[((size_t)(u & 0xffffu) << 7) + (l32 << 2)];
            }
            #pragma unroll
            for (int j = 0; j < 4; ++j) {
                ax += wv[j] * h2f((unsigned short)(g[j].x & 0xffffu));
                ay += wv[j] * h2f((unsigned short)(g[j].x >> 16));
                az += wv[j] * h2f((unsigned short)(g[j].y & 0xffffu));
                aw += wv[j] * h2f((unsigned short)(g[j].y >> 16));
            }
        }
        for (; i + 2 <= nb; i += 2) {
            uint2 g[2]; float wv[2];
            #pragma unroll
            for (int j = 0; j < 2; ++j) {
                unsigned u = __shfl(ce, i + j, 32);
                wv[j] = h2f((unsigned short)(u >> 16));
                g[j] = *(const uint2*)&hb[((size_t)(u & 0xffffu) << 7) + (l32 << 2)];
            }
            #pragma unroll
            for (int j = 0; j < 2; ++j) {
                ax += wv[j] * h2f((unsigned short)(g[j].x & 0xffffu));
                ay += wv[j] * h2f((unsigned short)(g[j].x >> 16));
                az += wv[j] * h2f((unsigned short)(g[j].y & 0xffffu));
                aw += wv[j] * h2f((unsigned short)(g[j].y >> 16));
            }
        }
        for (; i < nb; ++i) {
            unsigned u = __shfl(ce, i, 32);
            float w = h2f((unsigned short)(u >> 16));
            uint2 g = *(const uint2*)&hb[((size_t)(u & 0xffffu) << 7) + (l32 << 2)];
            ax += w * h2f((unsigned short)(g.x & 0xffffu));
            ay += w * h2f((unsigned short)(g.x >> 16));
            az += w * h2f((unsigned short)(g.y & 0xffffu));
            aw += w * h2f((unsigned short)(g.y >> 16));
        }
        e += nb;
    }
    uint2 o;
    o.x = (unsigned)f2h(ax) | ((unsigned)f2h(ay) << 16);
    o.y = (unsigned)f2h(az) | ((unsigned)f2h(aw) << 16);
    *(uint2*)&supb[((size_t)node << 7) + (l32 << 2)] = o;
}

// ---------------- input GEMM: relu(x@W_in + b) -> hb, h0b (fp16) ----------
// fp32 x converted to fp16 in staging; f16 MFMA; 48KB LDS -> 3 blocks/CU.

__global__ __launch_bounds__(256)
void gemm_in(const float* __restrict__ inA,
             const unsigned short* __restrict__ Bh,
             const float* __restrict__ bias,
             unsigned short* __restrict__ hb,
             unsigned short* __restrict__ h0b, int M) {
    extern __shared__ char lds[];
    char* Ah = lds;                  // 64*128 fp16 = 16KB
    char* Wh = Ah + 16384;           // 32KB

    const int tid  = threadIdx.x;
    const int row0 = blockIdx.x * 64;

    for (int c = tid; c < 1024; c += 256) {            // 64 rows x 16 chunks
        int row = c >> 4, k8 = c & 15;
        int grow = row0 + row;
        short8 hv = {0,0,0,0,0,0,0,0};
        if (grow < M) {
            const float* s = &inA[(size_t)grow * 128 + k8 * 8];
            float4 f0 = *(const float4*)s;
            float4 f1 = *(const float4*)(s + 4);
            float ff[8] = {f0.x, f0.y, f0.z, f0.w, f1.x, f1.y, f1.z, f1.w};
            #pragma unroll
            for (int j = 0; j < 8; ++j) hv[j] = (short)f2h(ff[j]);
        }
        *(short8*)(Ah + row * 256 + ((k8 ^ (row & 7)) << 4)) = hv;
    }
    for (int c = tid; c < 2048; c += 256) {
        int n = c >> 4, k8 = c & 15;
        *(short8*)(Wh + n * 256 + ((k8 ^ (n & 7)) << 4)) = *(const short8*)&Bh[n * 128 + k8 * 8];
    }
    __syncthreads();

    const int lane = tid & 63;
    const int w    = tid >> 6;
    const int lr   = lane & 15;
    const int lg   = lane >> 4;

    f32x4 acc[4][2];
    #pragma unroll
    for (int m = 0; m < 4; ++m)
        #pragma unroll
        for (int n2 = 0; n2 < 2; ++n2) acc[m][n2] = (f32x4){0.f, 0.f, 0.f, 0.f};

    #pragma unroll
    for (int kk = 0; kk < 4; ++kk) {
        int k8 = kk * 4 + lg;
        half8 a[4], b[2];
        #pragma unroll
        for (int m = 0; m < 4; ++m) {
            int row = m * 16 + lr;
            a[m] = *(const half8*)(Ah + row * 256 + ((k8 ^ (row & 7)) << 4));
        }
        #pragma unroll
        for (int n2 = 0; n2 < 2; ++n2) {
            int n = (w * 2 + n2) * 16 + lr;
            b[n2] = *(const half8*)(Wh + n * 256 + ((k8 ^ (n & 7)) << 4));
        }
        #pragma unroll
        for (int m = 0; m < 4; ++m)
            #pragma unroll
            for (int n2 = 0; n2 < 2; ++n2)
                acc[m][n2] = __builtin_amdgcn_mfma_f32_16x16x32_f16(a[m], b[n2], acc[m][n2], 0, 0, 0);
    }

    #pragma unroll
    for (int m = 0; m < 4; ++m) {
        #pragma unroll
        for (int n2 = 0; n2 < 2; ++n2) {
            int col = (w * 2 + n2) * 16 + lr;
            #pragma unroll
            for (int r = 0; r < 4; ++r) {
                int row = row0 + m * 16 + lg * 4 + r;
                if (row < M) {
                    float o = fmaxf(acc[m][n2][r] + bias[col], 0.f);
                    unsigned short ob = f2h(o);
                    hb [(size_t)row * 128 + col] = ob;
                    h0b[(size_t)row * 128 + col] = ob;
                }
            }
        }
    }
}

// ---------------- layer GEMM: relu(beta*(sup@W) + (1-beta)*sup) -----------
// fp16 in/out, f16 MFMA, residual from the staged LDS tile.

__global__ __launch_bounds__(256)
void gemm_layer(const unsigned short* __restrict__ supb,
                const unsigned short* __restrict__ Bh,
                float beta, float gamma,
                unsigned short* __restrict__ outh, int M) {
    extern __shared__ char lds[];
    char* Ah = lds;                  // 64*128 fp16 = 16KB
    char* Wh = Ah + 16384;           // 32KB

    const int tid  = threadIdx.x;
    const int row0 = blockIdx.x * 64;

    for (int c = tid; c < 1024; c += 256) {            // 64 rows x 16 chunks
        int row = c >> 4, k8 = c & 15;
        int grow = row0 + row;
        short8 hv = {0,0,0,0,0,0,0,0};
        if (grow < M) hv = *(const short8*)&supb[(size_t)grow * 128 + k8 * 8];
        *(short8*)(Ah + row * 256 + ((k8 ^ (row & 7)) << 4)) = hv;
    }
    for (int c = tid; c < 2048; c += 256) {
        int n = c >> 4, k8 = c & 15;
        *(short8*)(Wh + n * 256 + ((k8 ^ (n & 7)) << 4)) = *(const short8*)&Bh[n * 128 + k8 * 8];
    }
    __syncthreads();

    const int lane = tid & 63;
    const int w    = tid >> 6;
    const int lr   = lane & 15;
    const int lg   = lane >> 4;

    f32x4 acc[4][2];
    #pragma unroll
    for (int m = 0; m < 4; ++m)
        #pragma unroll
        for (int n2 = 0; n2 < 2; ++n2) acc[m][n2] = (f32x4){0.f, 0.f, 0.f, 0.f};

    #pragma unroll
    for (int kk = 0; kk < 4; ++kk) {
        int k8 = kk * 4 + lg;
        half8 a[4], b[2];
        #pragma unroll
        for (int m = 0; m < 4; ++m) {
            int row = m * 16 + lr;
            a[m] = *(const half8*)(Ah + row * 256 + ((k8 ^ (row & 7)) << 4));
        }
        #pragma unroll
        for (int n2 = 0; n2 < 2; ++n2) {
            int n = (w * 2 + n2) * 16 + lr;
            b[n2] = *(const half8*)(Wh + n * 256 + ((k8 ^ (n & 7)) << 4));
        }
        #pragma unroll
        for (int m = 0; m < 4; ++m)
            #pragma unroll
            for (int n2 = 0; n2 < 2; ++n2)
                acc[m][n2] = __builtin_amdgcn_mfma_f32_16x16x32_f16(a[m], b[n2], acc[m][n2], 0, 0, 0);
    }

    #pragma unroll
    for (int m = 0; m < 4; ++m) {
        #pragma unroll
        for (int n2 = 0; n2 < 2; ++n2) {
            int col = (w * 2 + n2) * 16 + lr;
            int k8c = col >> 3;
            int ebc = (col & 7) * 2;
            #pragma unroll
            for (int r = 0; r < 4; ++r) {
                int rl  = m * 16 + lg * 4 + r;
                int row = row0 + rl;
                if (row < M) {
                    unsigned short rb = *(const unsigned short*)
                        (Ah + rl * 256 + ((k8c ^ (rl & 7)) << 4) + ebc);
                    float o = beta * acc[m][n2][r] + gamma * h2f(rb);
                    o = fmaxf(o, 0.f);
                    outh[(size_t)row * 128 + col] = f2h(o);
                }
            }
        }
    }
}

// ---------------- output GEMM (MFMA): [M,128]fp16 @ [128,48]fp16 + b ------
// 64-row tile, 4 waves (wave w = rows w*16..w*16+15), 3 n-frags (48 cols,
// cols >= C masked). 28KB LDS.

__global__ __launch_bounds__(256)
void k_out(const unsigned short* __restrict__ hb,
           const unsigned short* __restrict__ Wot,
           const float* __restrict__ bias,
           float* __restrict__ out, int M, int C) {
    extern __shared__ char lds[];
    char* Ah = lds;                  // 64*128 fp16 = 16KB
    char* Wh = Ah + 16384;           // 48*128 fp16 = 12KB

    const int tid  = threadIdx.x;
    const int row0 = blockIdx.x * 64;

    for (int c = tid; c < 1024; c += 256) {
        int row = c >> 4, k8 = c & 15;
        int grow = row0 + row;
        short8 hv = {0,0,0,0,0,0,0,0};
        if (grow < M) hv = *(const short8*)&hb[(size_t)grow * 128 + k8 * 8];
        *(short8*)(Ah + row * 256 + ((k8 ^ (row & 7)) << 4)) = hv;
    }
    for (int c = tid; c < 768; c += 256) {             // 48 rows x 16 chunks
        int n = c >> 4, k8 = c & 15;
        *(short8*)(Wh + n * 256 + ((k8 ^ (n & 7)) << 4)) = *(const short8*)&Wot[n * 128 + k8 * 8];
    }
    __syncthreads();

    const int lane = tid & 63;
    const int w    = tid >> 6;        // wave w -> rows w*16..w*16+15
    const int lr   = lane & 15;
    const int lg   = lane >> 4;

    f32x4 acc[3];
    #pragma unroll
    for (int n2 = 0; n2 < 3; ++n2) acc[n2] = (f32x4){0.f, 0.f, 0.f, 0.f};

    #pragma unroll
    for (int kk = 0; kk < 4; ++kk) {
        int k8 = kk * 4 + lg;
        int row = w * 16 + lr;
        half8 a = *(const half8*)(Ah + row * 256 + ((k8 ^ (row & 7)) << 4));
        #pragma unroll
        for (int n2 = 0; n2 < 3; ++n2) {
            int n = n2 * 16 + lr;
            half8 b = *(const half8*)(Wh + n * 256 + ((k8 ^ (n & 7)) << 4));
            acc[n2] = __builtin_amdgcn_mfma_f32_16x16x32_f16(a, b, acc[n2], 0, 0, 0);
        }
    }

    #pragma unroll
    for (int n2 = 0; n2 < 3; ++n2) {
        int col = n2 * 16 + lr;
        if (col < C) {
            float bb = bias[col];
            #pragma unroll
            for (int r = 0; r < 4; ++r) {
                int row = row0 + w * 16 + lg * 4 + r;
                if (row < M) out[(size_t)row * C + col] = acc[n2][r] + bb;
            }
        }
    }
}

// ---------------- host ----------------

extern "C" void kernel_launch(void* const* d_in, const int* in_sizes, int n_in,
                              void* d_out, int out_size, void* d_ws, size_t ws_size,
                              hipStream_t stream) {
    const float* x        = (const float*)d_in[0];
    const int*   ei       = (const int*)d_in[1];
    const float* W_in     = (const float*)d_in[2];
    const float* b_in     = (const float*)d_in[3];
    const float* W_layers = (const float*)d_in[4];
    const float* W_out    = (const float*)d_in[5];
    const float* b_out    = (const float*)d_in[6];
    float* out = (float*)d_out;

    const int H = 128;
    const int N = in_sizes[0] / H;             // 50000 (< 65536 for packed CSR)
    const int E = in_sizes[1] / 2;             // 800000
    const int L = in_sizes[4] / (H * H);       // 4
    const int C = in_sizes[5] / H;             // 40

    char* p = (char*)d_ws;
    auto alloc = [&](size_t bytes) {
        char* r = p;
        p += (bytes + 255) & ~(size_t)255;
        return r;
    };
    int*      cnt   = (int*)alloc((size_t)N * 4);
    int*      offs  = (int*)alloc((size_t)(N + 1) * 4);
    int*      parts = (int*)alloc(256 * 4);
    unsigned* csr   = (unsigned*)alloc((size_t)E * 4);
    unsigned short* rank = (unsigned short*)alloc((size_t)E * 2);
    float*    dinv  = (float*)alloc((size_t)N * 4);
    unsigned short* hb   = (unsigned short*)alloc((size_t)N * H * 2);
    unsigned short* h0b  = (unsigned short*)alloc((size_t)N * H * 2);
    unsigned short* supb = (unsigned short*)alloc((size_t)N * H * 2);
    unsigned short* wt   = (unsigned short*)alloc((size_t)L * H * H * 2);
    unsigned short* wint = (unsigned short*)alloc((size_t)H * H * 2);
    unsigned short* wot  = (unsigned short*)alloc((size_t)48 * H * 2);
    (void)ws_size;

    const int* ei0 = ei;        // destinations (row)
    const int* ei1 = ei + E;    // sources (col)

    const int nblkN = (N + 255) / 256;
    const int nblkE = (E + 255) / 256;

    k_wprep<<<6, 256, 0, stream>>>(W_layers, W_in, W_out, wt, wint, wot, C);

    hipMemsetAsync(cnt, 0, (size_t)N * 4, stream);
    k_count<<<nblkE, 256, 0, stream>>>(ei0, cnt, rank, E);
    k_scan_part<<<nblkN, 256, 0, stream>>>(cnt, offs, parts, dinv, N);
    k_scan_tops<<<1, 256, 0, stream>>>(parts, nblkN);
    k_scan_add<<<nblkN, 256, 0, stream>>>(offs, parts, N, E);
    k_scatter<<<nblkE, 256, 0, stream>>>(ei0, ei1, rank, offs, dinv, csr, E);

    // input linear + relu -> hb, h0b (fp16)
    gemm_in<<<(N + 63) / 64, 256, 48 * 1024, stream>>>(x, wint, b_in, hb, h0b, N);

    for (int l = 0; l < L; ++l) {
        float beta = logf(0.5f / (float)(l + 1) + 1.0f);
        k_spmm<<<(N + 7) / 8, 256, 0, stream>>>(offs, csr, hb, h0b, dinv, supb, N, E);
        gemm_layer<<<(N + 63) / 64, 256, 48 * 1024, stream>>>(
            supb, wt + (size_t)l * H * H, beta, 1.0f - beta, hb, N);
    }

    k_out<<<(N + 63) / 64, 256, 28 * 1024, stream>>>(hb, wot, b_out, out, N, C);
}